// Round 6
// baseline (810.510 us; speedup 1.0000x reference)
//
#include <hip/hip_runtime.h>
#include <stdint.h>

typedef unsigned int u32;
typedef unsigned long long u64;

#define KSEL 6000      // pre_nms_limit
#define PC   1000      // proposal_count
#define NW   94        // ceil(KSEL/64) removal-mask words
#define CAP  8000      // candidate collection cap (threshold-bin pop ~400 -> ~6400 used)
#define CH   2048      // elements per histogram block

// broadcast lane `src` (wave-uniform) of a per-lane u64 to all lanes (SGPR result)
__device__ inline u64 bcast64(u64 v, int src) {
    int s = __builtin_amdgcn_readfirstlane(src);
    u32 lo = __builtin_amdgcn_readlane((u32)(v & 0xFFFFFFFFULL), s);
    u32 hi = __builtin_amdgcn_readlane((u32)(v >> 32), s);
    return ((u64)hi << 32) | lo;
}
__device__ inline u64 shflx64(u64 v, int m) {
    int lo = __shfl_xor((int)(u32)(v & 0xFFFFFFFFULL), m);
    int hi = __shfl_xor((int)(u32)(v >> 32), m);
    return ((u64)(u32)hi << 32) | (u32)lo;
}

// suffix-scan pick over a 256-bin histogram (block of 256 threads).
// Finds bin with suffix(bin) >= rem > suffix(bin+1); outputs bin and rem - suffix(bin+1).
__device__ void pick256(const u32* __restrict__ h, u32 rem_in, u32* s /*LDS >=258*/,
                        u32* out_bin, u32* out_rem)
{
    const int t = threadIdx.x;
    s[t] = h[t];
    __syncthreads();
    for (int off = 1; off < 256; off <<= 1) {
        u32 add = (t + off < 256) ? s[t + off] : 0u;
        __syncthreads();
        s[t] += add;
        __syncthreads();
    }
    u32 suf = s[t];
    u32 sufn = (t < 255) ? s[t + 1] : 0u;
    if (suf >= rem_in && sufn < rem_in) { s[256] = (u32)t; s[257] = rem_in - sufn; }
    __syncthreads();
    *out_bin = s[256];
    *out_rem = s[257];
}

// ---------------- K0: keys + top-8-bit histogram (LDS-privatized) ----------------
__global__ __launch_bounds__(256)
void k_keys_hist8(const float* __restrict__ probs, u32* __restrict__ keys,
                  u32* __restrict__ hist8a, int A)
{
    __shared__ u32 lh[4][256];
    const int tid = threadIdx.x, b = blockIdx.y;
    const int w = tid >> 6;
    for (int q = tid; q < 1024; q += 256) ((u32*)lh)[q] = 0;
    __syncthreads();
    int base = blockIdx.x * CH;
#pragma unroll
    for (int it = 0; it < CH / 256; ++it) {
        int a = base + it * 256 + tid;
        if (a < A) {
            size_t i = (size_t)b * A + a;
            u32 u = __float_as_uint(probs[i * 2 + 1]);
            u = (u & 0x80000000u) ? ~u : (u | 0x80000000u);   // float order -> uint order
            keys[i] = u;
            atomicAdd(&lh[w][u >> 24], 1u);
        }
    }
    __syncthreads();
    u32 s = lh[0][tid] + lh[1][tid] + lh[2][tid] + lh[3][tid];
    if (s) atomicAdd(&hist8a[b * 256 + tid], s);
}

// ---------------- K1: second-8-bit histogram (pick0 recomputed inline) ----------------
__global__ __launch_bounds__(256)
void k_hist8b(const u32* __restrict__ keys, const u32* __restrict__ hist8a,
              u32* __restrict__ hist8b, int A)
{
    __shared__ u32 ps[258];
    __shared__ u32 lh[4][256];
    const int tid = threadIdx.x, b = blockIdx.y;
    const int w = tid >> 6;
    u32 pfxA, remA;
    pick256(hist8a + b * 256, (u32)KSEL, ps, &pfxA, &remA);
    for (int q = tid; q < 1024; q += 256) ((u32*)lh)[q] = 0;
    __syncthreads();
    int base = blockIdx.x * CH;
#pragma unroll
    for (int it = 0; it < CH / 256; ++it) {
        int a = base + it * 256 + tid;
        if (a < A) {
            u32 k = keys[(size_t)b * A + a];
            if ((k >> 24) == pfxA) atomicAdd(&lh[w][(k >> 16) & 0xFFu], 1u);
        }
    }
    __syncthreads();
    u32 s = lh[0][tid] + lh[1][tid] + lh[2][tid] + lh[3][tid];
    if (s) atomicAdd(&hist8b[b * 256 + tid], s);
}

// ---------------- K2: collect (~key,index) for keys >= T (both picks inline) ----------------
__global__ __launch_bounds__(256)
void k_collect(const u32* __restrict__ keys, const u32* __restrict__ hist8a,
               const u32* __restrict__ hist8b, u32* __restrict__ cnt,
               u64* __restrict__ cand, int A)
{
    __shared__ u32 ps[258];
    const int b = blockIdx.y;
    u32 pfxA, remA, binB, remB;
    pick256(hist8a + b * 256, (u32)KSEL, ps, &pfxA, &remA);
    pick256(hist8b + b * 256, remA, ps, &binB, &remB);
    const u32 T = ((pfxA << 8) | binB) << 16;   // floor of threshold 16-bit bin
    int a = blockIdx.x * 256 + threadIdx.x;
    if (a >= A) return;
    u32 k = keys[(size_t)b * A + a];
    if (k >= T) {
        u32 pos = atomicAdd(&cnt[b], 1u);
        if (pos < CAP) cand[(size_t)b * CAP + pos] = ((u64)(~k) << 32) | (u32)a;
    }
}

// ---------------- K3: per-sample stable sort (score desc, idx asc) + box decode ----------------
__global__ __launch_bounds__(1024)
void k_sortdecode(const float* __restrict__ probs, const float* __restrict__ deltas,
                  const float* __restrict__ anchors, const u64* __restrict__ cand,
                  const u32* __restrict__ cntg, float* __restrict__ boxes_sel,
                  float* __restrict__ scores_sel, int A)
{
    __shared__ u64 sbuf[8192];                 // 64 KiB
    const int tid = threadIdx.x, b = blockIdx.x;
    int cnt = (int)cntg[b]; if (cnt > CAP) cnt = CAP;
    for (int i = tid; i < cnt; i += 1024) sbuf[i] = cand[(size_t)b * CAP + i];
    for (int i = cnt + tid; i < 8192; i += 1024) sbuf[i] = ~0ULL;
    __syncthreads();

    for (int kk = 2; kk <= 8192; kk <<= 1)
        for (int jj = kk >> 1; jj > 0; jj >>= 1) {
            for (int i = tid; i < 8192; i += 1024) {
                int ixj = i ^ jj;
                if (ixj > i) {
                    u64 x = sbuf[i], y = sbuf[ixj];
                    bool up = ((i & kk) == 0);
                    if ((x > y) == up) { sbuf[i] = y; sbuf[ixj] = x; }
                }
            }
            __syncthreads();
        }

    for (int s = tid; s < KSEL; s += 1024) {
        u64 ck = sbuf[s];
        int a = (int)(u32)ck;
        float score = probs[((size_t)b * A + a) * 2 + 1];
        float4 an = ((const float4*)anchors)[a];
        float4 dl = ((const float4*)deltas)[(size_t)b * A + a];
        float h = an.z - an.x, w = an.w - an.y;
        float cy = an.x + 0.5f * h + dl.x * 0.1f * h;
        float cx = an.y + 0.5f * w + dl.y * 0.1f * w;
        h *= expf(dl.z * 0.2f);
        w *= expf(dl.w * 0.2f);
        float y1 = cy - 0.5f * h, x1 = cx - 0.5f * w;
        float y2 = y1 + h,        x2 = x1 + w;
        y1 = fminf(fmaxf(y1, 0.f), 1024.f);
        x1 = fminf(fmaxf(x1, 0.f), 1024.f);
        y2 = fminf(fmaxf(y2, 0.f), 1024.f);
        x2 = fminf(fmaxf(x2, 0.f), 1024.f);
        ((float4*)boxes_sel)[(size_t)b * KSEL + s] = make_float4(y1, x1, y2, x2);
        scores_sel[(size_t)b * KSEL + s] = score;
    }
}

// ---------------- K4: suppression mask matrix (upper triangle only) ----------------
__global__ __launch_bounds__(64)
void k_iou(const float* __restrict__ boxes_sel, u64* __restrict__ mask)
{
    __shared__ float4 rowb[64];
    int t = threadIdx.x;
    int bi = blockIdx.x, bj = blockIdx.y, b = blockIdx.z;
    if (bj < bi) return;
    const float4* boxes = (const float4*)boxes_sel + (size_t)b * KSEL;
    int ri = bi * 64 + t;
    int j  = bj * 64 + t;
    rowb[t] = (ri < KSEL) ? boxes[ri] : make_float4(0.f, 0.f, 0.f, 0.f);
    float4 cb = (j < KSEL) ? boxes[j] : make_float4(0.f, 0.f, 0.f, 0.f);
    float areaC = (cb.z - cb.x) * (cb.w - cb.y);
    __syncthreads();
    u64 myword = 0;
    for (int r = 0; r < 64; ++r) {
        float4 rb = rowb[r];
        float areaR = (rb.z - rb.x) * (rb.w - rb.y);
        float iy1 = fmaxf(rb.x, cb.x), ix1 = fmaxf(rb.y, cb.y);
        float iy2 = fminf(rb.z, cb.z), ix2 = fminf(rb.w, cb.w);
        float inter = fmaxf(iy2 - iy1, 0.f) * fmaxf(ix2 - ix1, 0.f);
        float uni = fmaxf(areaR + areaC - inter, 1e-10f);
        bool sup = (j < KSEL) && (inter > 0.7f * uni);
        u64 word = __ballot(sup ? 1 : 0);
        if (r == t) myword = word;
    }
    if (ri < KSEL) mask[((size_t)b * KSEL + ri) * NW + bj] = myword;
}

// ---------------- K5: greedy NMS, urgent/deferred split + fused output ----------------
// Per chunk the ONLY value chunk c+1 needs is word c+1 of chunk-c kept rows:
// load those 8B words lane-parallel (one round trip, shfl-reduced). Full rows are
// loaded into compile-time-indexed registers and merged one chunk LATER (latency hidden).
__global__ __launch_bounds__(64)
void k_nms_out(const u64* __restrict__ mask,
               const float* __restrict__ boxes_sel, const float* __restrict__ scores_sel,
               float* __restrict__ out, int B)
{
    __shared__ int ki[PC];
    const int lane = threadIdx.x;
    const int b = blockIdx.x;
    const u64* mb = mask + (size_t)b * KSEL * NW;

    u64 remv0 = 0, remv1 = 0;          // lane l holds removal words l and 64+l
    int kept = 0;
    u64 urgentW = 0;                   // OR of prev-chunk kept rows' word (cur chunk)
    u64 dtv0[16], dtv1[16], dvm[16];   // deferred bulk rows (prev chunk)
#pragma unroll
    for (int q = 0; q < 16; ++q) { dtv0[q] = 0; dtv1[q] = 0; dvm[q] = 0; }
    u64 mcur = mb[(size_t)lane * NW];  // chunk 0 diagonal word

    for (int c = 0; c < NW; ++c) {
        int rin = (c + 1) * 64 + lane;                       // prefetch next diagonal
        u64 mnext = (c + 1 < NW && rin < KSEL) ? mb[(size_t)rin * NW + (c + 1)] : 0ULL;

        u64 r = ((c < 64) ? bcast64(remv0, c) : bcast64(remv1, c - 64)) | urgentW;
        int rbn = KSEL - c * 64;
        u64 valid = (rbn >= 64) ? ~0ULL : ((1ULL << rbn) - 1ULL);
        u64 pend = valid & ~r;
        u64 keep = 0;
        while (pend) {                                       // wave-uniform greedy resolve
            int bb = (int)(__ffsll((unsigned long long)pend) - 1);
            keep |= 1ULL << bb;
            u64 sup = bcast64(mcur, bb);
            pend &= ~(sup | (1ULL << bb));
        }
        int m = __popcll((unsigned long long)keep);

        int mybit = 0;                                       // lane-th kept bit
        {
            u64 kk = keep; int q = 0;
            while (kk) {
                int bb = (int)(__ffsll((unsigned long long)kk) - 1); kk &= kk - 1;
                if (q == lane) mybit = bb;
                if (lane == 0 && kept + q < PC) ki[kept + q] = c * 64 + bb;
                ++q;
            }
        }
        kept += m;
        if (kept >= PC) { kept = PC; break; }
        if (c + 1 == NW) break;

        // merge deferred bulk from previous chunk (loads issued ~1 chunk ago)
#pragma unroll
        for (int q = 0; q < 16; ++q) { remv0 |= dtv0[q] & dvm[q]; remv1 |= dtv1[q] & dvm[q]; }

        if (m) {
            // urgent: word (c+1) of each kept row, lane-parallel, OR-reduce
            u64 uval = 0;
            if (lane < m)
                uval = mb[(size_t)(c * 64 + mybit) * NW + (c + 1)];
#pragma unroll
            for (int off = 1; off < 64; off <<= 1) uval |= shflx64(uval, off);
            urgentW = uval;

            // deferred bulk: first <=16 kept rows into registers, consumed next chunk
            int m16 = (m < 16) ? m : 16;
#pragma unroll
            for (int q = 0; q < 16; ++q) {
                int rowq = __builtin_amdgcn_readlane(mybit, q);
                bool v = (q < m16);
                int rr = c * 64 + (v ? rowq : 0);
                const u64* row = mb + (size_t)rr * NW;
                dtv0[q] = row[lane];
                dtv1[q] = (lane < NW - 64) ? row[64 + lane] : 0ULL;
                dvm[q] = v ? ~0ULL : 0ULL;
            }
            // rare slow path: rows beyond 16 merged immediately
            if (m > 16) {
                u64 kk = keep;
#pragma unroll
                for (int drop = 0; drop < 16; ++drop) kk &= kk - 1;
                while (kk) {
                    int bb = (int)(__ffsll((unsigned long long)kk) - 1); kk &= kk - 1;
                    const u64* row = mb + (size_t)(c * 64 + bb) * NW;
                    remv0 |= row[lane];
                    if (lane < NW - 64) remv1 |= row[64 + lane];
                }
            }
        } else {
            urgentW = 0;
#pragma unroll
            for (int q = 0; q < 16; ++q) dvm[q] = 0;
        }
        mcur = mnext;
    }

    // ---- fused output: gather kept, normalize, zero tail, write n ----
    const float4* bx = (const float4*)boxes_sel + (size_t)b * KSEL;
    const float*  sc = scores_sel + (size_t)b * KSEL;
    float4* ob = (float4*)(out + (size_t)b * PC * 4);
    float*  os = out + (size_t)B * PC * 4 + (size_t)b * PC;
    for (int s = lane; s < PC; s += 64) {
        float4 v = make_float4(0.f, 0.f, 0.f, 0.f);
        float sv = 0.f;
        if (s < kept) {
            int i = ki[s];
            float4 t = bx[i];
            v = make_float4(t.x * (1.f/1024.f), t.y * (1.f/1024.f),
                            t.z * (1.f/1024.f), t.w * (1.f/1024.f));
            sv = sc[i];
        }
        ob[s] = v;
        os[s] = sv;
    }
    if (lane == 0) out[(size_t)B * PC * 5 + b] = (float)kept;
}

extern "C" void kernel_launch(void* const* d_in, const int* in_sizes, int n_in,
                              void* d_out, int out_size, void* d_ws, size_t ws_size,
                              hipStream_t stream)
{
    const float* probs   = (const float*)d_in[0];
    const float* deltas  = (const float*)d_in[1];
    const float* anchors = (const float*)d_in[2];
    int A = in_sizes[2] / 4;
    int B = in_sizes[0] / (2 * A);

    char* w = (char*)d_ws;
    size_t off = 0;
    // zero region (single tiny memset): hist8a | hist8b | cnt
    u32* hist8a = (u32*)(w + off);     off += (size_t)B * 256 * sizeof(u32);
    u32* hist8b = (u32*)(w + off);     off += (size_t)B * 256 * sizeof(u32);
    u32* cnt    = (u32*)(w + off);     off += (size_t)B * sizeof(u32);
    size_t zero_bytes = off;
    off = (off + 15) & ~(size_t)15;
    u32* keys = (u32*)(w + off);       off += (size_t)B * A * sizeof(u32);
    off = (off + 15) & ~(size_t)15;
    u64* cand = (u64*)(w + off);       off += (size_t)B * CAP * sizeof(u64);
    float* boxes_sel  = (float*)(w + off); off += (size_t)B * KSEL * 4 * sizeof(float);
    float* scores_sel = (float*)(w + off); off += (size_t)B * KSEL * sizeof(float);
    off = (off + 15) & ~(size_t)15;
    u64* mask = (u64*)(w + off);           off += (size_t)B * KSEL * NW * sizeof(u64);

    hipMemsetAsync(hist8a, 0, zero_bytes, stream);

    dim3 gCH((A + CH - 1) / CH, B);
    dim3 gA((A + 255) / 256, B);
    k_keys_hist8<<<gCH, 256, 0, stream>>>(probs, keys, hist8a, A);
    k_hist8b<<<gCH, 256, 0, stream>>>(keys, hist8a, hist8b, A);
    k_collect<<<gA, 256, 0, stream>>>(keys, hist8a, hist8b, cnt, cand, A);
    k_sortdecode<<<B, 1024, 0, stream>>>(probs, deltas, anchors, cand, cnt,
                                         boxes_sel, scores_sel, A);
    k_iou<<<dim3(NW, NW, B), 64, 0, stream>>>(boxes_sel, mask);
    k_nms_out<<<B, 64, 0, stream>>>(mask, boxes_sel, scores_sel, (float*)d_out, B);
}

// Round 8
// 576.032 us; speedup vs baseline: 1.4071x; 1.4071x over previous
//
#include <hip/hip_runtime.h>
#include <stdint.h>

typedef unsigned int u32;
typedef unsigned long long u64;

#define KSEL 6000      // pre_nms_limit
#define PC   1000      // proposal_count
#define NW   94        // ceil(KSEL/64) removal-mask words
#define CAP  8000      // candidate collection cap
#define CH   2048      // elements per histogram block

// broadcast lane `src` (wave-uniform) of a per-lane u64 to all lanes (SGPR result)
__device__ inline u64 bcast64(u64 v, int src) {
    int s = __builtin_amdgcn_readfirstlane(src);
    u32 lo = __builtin_amdgcn_readlane((u32)(v & 0xFFFFFFFFULL), s);
    u32 hi = __builtin_amdgcn_readlane((u32)(v >> 32), s);
    return ((u64)hi << 32) | lo;
}

// suffix-scan pick over a 256-bin histogram (block of 256 threads).
__device__ void pick256(const u32* __restrict__ h, u32 rem_in, u32* s /*LDS >=258*/,
                        u32* out_bin, u32* out_rem)
{
    const int t = threadIdx.x;
    s[t] = h[t];
    __syncthreads();
    for (int off = 1; off < 256; off <<= 1) {
        u32 add = (t + off < 256) ? s[t + off] : 0u;
        __syncthreads();
        s[t] += add;
        __syncthreads();
    }
    u32 suf = s[t];
    u32 sufn = (t < 255) ? s[t + 1] : 0u;
    if (suf >= rem_in && sufn < rem_in) { s[256] = (u32)t; s[257] = rem_in - sufn; }
    __syncthreads();
    *out_bin = s[256];
    *out_rem = s[257];
}

// ---------------- K0: keys + top-8-bit histogram (LDS-privatized) ----------------
__global__ __launch_bounds__(256)
void k_keys_hist8(const float* __restrict__ probs, u32* __restrict__ keys,
                  u32* __restrict__ hist8a, int A)
{
    __shared__ u32 lh[4][256];
    const int tid = threadIdx.x, b = blockIdx.y;
    const int w = tid >> 6;
    for (int q = tid; q < 1024; q += 256) ((u32*)lh)[q] = 0;
    __syncthreads();
    int base = blockIdx.x * CH;
#pragma unroll
    for (int it = 0; it < CH / 256; ++it) {
        int a = base + it * 256 + tid;
        if (a < A) {
            size_t i = (size_t)b * A + a;
            u32 u = __float_as_uint(probs[i * 2 + 1]);
            u = (u & 0x80000000u) ? ~u : (u | 0x80000000u);   // float order -> uint order
            keys[i] = u;
            atomicAdd(&lh[w][u >> 24], 1u);
        }
    }
    __syncthreads();
    u32 s = lh[0][tid] + lh[1][tid] + lh[2][tid] + lh[3][tid];
    if (s) atomicAdd(&hist8a[b * 256 + tid], s);
}

// ---------------- K1: second-8-bit histogram (pick0 recomputed inline) ----------------
__global__ __launch_bounds__(256)
void k_hist8b(const u32* __restrict__ keys, const u32* __restrict__ hist8a,
              u32* __restrict__ hist8b, int A)
{
    __shared__ u32 ps[258];
    __shared__ u32 lh[4][256];
    const int tid = threadIdx.x, b = blockIdx.y;
    const int w = tid >> 6;
    u32 pfxA, remA;
    pick256(hist8a + b * 256, (u32)KSEL, ps, &pfxA, &remA);
    for (int q = tid; q < 1024; q += 256) ((u32*)lh)[q] = 0;
    __syncthreads();
    int base = blockIdx.x * CH;
#pragma unroll
    for (int it = 0; it < CH / 256; ++it) {
        int a = base + it * 256 + tid;
        if (a < A) {
            u32 k = keys[(size_t)b * A + a];
            if ((k >> 24) == pfxA) atomicAdd(&lh[w][(k >> 16) & 0xFFu], 1u);
        }
    }
    __syncthreads();
    u32 s = lh[0][tid] + lh[1][tid] + lh[2][tid] + lh[3][tid];
    if (s) atomicAdd(&hist8b[b * 256 + tid], s);
}

// ---------------- K2: collect (~key,index) for keys >= T ----------------
__global__ __launch_bounds__(256)
void k_collect(const u32* __restrict__ keys, const u32* __restrict__ hist8a,
               const u32* __restrict__ hist8b, u32* __restrict__ cnt,
               u64* __restrict__ cand, int A)
{
    __shared__ u32 ps[258];
    const int b = blockIdx.y;
    u32 pfxA, remA, binB, remB;
    pick256(hist8a + b * 256, (u32)KSEL, ps, &pfxA, &remA);
    pick256(hist8b + b * 256, remA, ps, &binB, &remB);
    const u32 T = ((pfxA << 8) | binB) << 16;   // floor of threshold 16-bit bin
    int a = blockIdx.x * 256 + threadIdx.x;
    if (a >= A) return;
    u32 k = keys[(size_t)b * A + a];
    if (k >= T) {
        u32 pos = atomicAdd(&cnt[b], 1u);
        if (pos < CAP) cand[(size_t)b * CAP + pos] = ((u64)(~k) << 32) | (u32)a;
    }
}

// ---------------- K3: per-sample stable sort + box decode ----------------
// Bitonic 8192 with jj<=4 stages fused into registers (8 contiguous elems/thread).
// LDS index padded (i + (i>>3)) to avoid 64B-stride bank conflicts on the fused reads.
__device__ inline int sphys(int i) { return i + (i >> 3); }
#define CSU(a, b) { if (a > b) { u64 _t = a; a = b; b = _t; } }
#define CSD(a, b) { if (b > a) { u64 _t = a; a = b; b = _t; } }
#define CSV(a, b) { if ((a > b) == up) { u64 _t = a; a = b; b = _t; } }

__global__ __launch_bounds__(1024)
void k_sortdecode(const float* __restrict__ probs, const float* __restrict__ deltas,
                  const float* __restrict__ anchors, const u64* __restrict__ cand,
                  const u32* __restrict__ cntg, float* __restrict__ boxes_sel,
                  float* __restrict__ scores_sel, int A)
{
    __shared__ u64 sbuf[9216];                 // 8192 + pad, 72 KiB
    const int tid = threadIdx.x, b = blockIdx.x;
    int cnt = (int)cntg[b]; if (cnt > CAP) cnt = CAP;
    for (int i = tid; i < cnt; i += 1024) sbuf[sphys(i)] = cand[(size_t)b * CAP + i];
    for (int i = cnt + tid; i < 8192; i += 1024) sbuf[sphys(i)] = ~0ULL;
    __syncthreads();

    const int base = tid * 8;
    const int pb = 9 * tid;                    // sphys(base)
    // levels kk=2,4,8 fully in registers
    {
        u64 e0 = sbuf[pb+0], e1 = sbuf[pb+1], e2 = sbuf[pb+2], e3 = sbuf[pb+3];
        u64 e4 = sbuf[pb+4], e5 = sbuf[pb+5], e6 = sbuf[pb+6], e7 = sbuf[pb+7];
        CSU(e0,e1); CSD(e2,e3); CSU(e4,e5); CSD(e6,e7);            // kk=2
        CSU(e0,e2); CSU(e1,e3); CSD(e4,e6); CSD(e5,e7);            // kk=4 jj=2
        CSU(e0,e1); CSU(e2,e3); CSD(e4,e5); CSD(e6,e7);            // kk=4 jj=1
        bool up = ((base & 8) == 0);                               // kk=8
        CSV(e0,e4); CSV(e1,e5); CSV(e2,e6); CSV(e3,e7);
        CSV(e0,e2); CSV(e1,e3); CSV(e4,e6); CSV(e5,e7);
        CSV(e0,e1); CSV(e2,e3); CSV(e4,e5); CSV(e6,e7);
        sbuf[pb+0]=e0; sbuf[pb+1]=e1; sbuf[pb+2]=e2; sbuf[pb+3]=e3;
        sbuf[pb+4]=e4; sbuf[pb+5]=e5; sbuf[pb+6]=e6; sbuf[pb+7]=e7;
    }
    __syncthreads();

    for (int kk = 16; kk <= 8192; kk <<= 1) {
        for (int jj = kk >> 1; jj >= 8; jj >>= 1) {
            for (int i = tid; i < 8192; i += 1024) {
                int ixj = i ^ jj;
                if (ixj > i) {
                    u64 x = sbuf[sphys(i)], y = sbuf[sphys(ixj)];
                    bool u2 = ((i & kk) == 0);
                    if ((x > y) == u2) { sbuf[sphys(i)] = y; sbuf[sphys(ixj)] = x; }
                }
            }
            __syncthreads();
        }
        {   // fused jj=4,2,1 in registers
            bool up = ((base & kk) == 0);
            u64 e0 = sbuf[pb+0], e1 = sbuf[pb+1], e2 = sbuf[pb+2], e3 = sbuf[pb+3];
            u64 e4 = sbuf[pb+4], e5 = sbuf[pb+5], e6 = sbuf[pb+6], e7 = sbuf[pb+7];
            CSV(e0,e4); CSV(e1,e5); CSV(e2,e6); CSV(e3,e7);
            CSV(e0,e2); CSV(e1,e3); CSV(e4,e6); CSV(e5,e7);
            CSV(e0,e1); CSV(e2,e3); CSV(e4,e5); CSV(e6,e7);
            sbuf[pb+0]=e0; sbuf[pb+1]=e1; sbuf[pb+2]=e2; sbuf[pb+3]=e3;
            sbuf[pb+4]=e4; sbuf[pb+5]=e5; sbuf[pb+6]=e6; sbuf[pb+7]=e7;
        }
        __syncthreads();
    }

    for (int s = tid; s < KSEL; s += 1024) {
        u64 ck = sbuf[sphys(s)];
        int a = (int)(u32)ck;
        float score = probs[((size_t)b * A + a) * 2 + 1];
        float4 an = ((const float4*)anchors)[a];
        float4 dl = ((const float4*)deltas)[(size_t)b * A + a];
        float h = an.z - an.x, w = an.w - an.y;
        float cy = an.x + 0.5f * h + dl.x * 0.1f * h;
        float cx = an.y + 0.5f * w + dl.y * 0.1f * w;
        h *= expf(dl.z * 0.2f);
        w *= expf(dl.w * 0.2f);
        float y1 = cy - 0.5f * h, x1 = cx - 0.5f * w;
        float y2 = y1 + h,        x2 = x1 + w;
        y1 = fminf(fmaxf(y1, 0.f), 1024.f);
        x1 = fminf(fmaxf(x1, 0.f), 1024.f);
        y2 = fminf(fmaxf(y2, 0.f), 1024.f);
        x2 = fminf(fmaxf(x2, 0.f), 1024.f);
        ((float4*)boxes_sel)[(size_t)b * KSEL + s] = make_float4(y1, x1, y2, x2);
        scores_sel[(size_t)b * KSEL + s] = score;
    }
}

// ---------------- K4: suppression mask matrix (upper triangle only) ----------------
__global__ __launch_bounds__(64)
void k_iou(const float* __restrict__ boxes_sel, u64* __restrict__ mask)
{
    __shared__ float4 rowb[64];
    int t = threadIdx.x;
    int bi = blockIdx.x, bj = blockIdx.y, b = blockIdx.z;
    if (bj < bi) return;
    const float4* boxes = (const float4*)boxes_sel + (size_t)b * KSEL;
    int ri = bi * 64 + t;
    int j  = bj * 64 + t;
    rowb[t] = (ri < KSEL) ? boxes[ri] : make_float4(0.f, 0.f, 0.f, 0.f);
    float4 cb = (j < KSEL) ? boxes[j] : make_float4(0.f, 0.f, 0.f, 0.f);
    float areaC = (cb.z - cb.x) * (cb.w - cb.y);
    __syncthreads();
    u64 myword = 0;
    for (int r = 0; r < 64; ++r) {
        float4 rb = rowb[r];
        float areaR = (rb.z - rb.x) * (rb.w - rb.y);
        float iy1 = fmaxf(rb.x, cb.x), ix1 = fmaxf(rb.y, cb.y);
        float iy2 = fminf(rb.z, cb.z), ix2 = fminf(rb.w, cb.w);
        float inter = fmaxf(iy2 - iy1, 0.f) * fmaxf(ix2 - ix1, 0.f);
        float uni = fmaxf(areaR + areaC - inter, 1e-10f);
        bool sup = (j < KSEL) && (inter > 0.7f * uni);
        u64 word = __ballot(sup ? 1 : 0);
        if (r == t) myword = word;
    }
    if (ri < KSEL) mask[((size_t)b * KSEL + ri) * NW + bj] = myword;
}

// ---------------- K5: greedy NMS (batch-8 named-register row-OR) + fused output ----------------
__global__ __launch_bounds__(64, 1)
void k_nms_out(const u64* __restrict__ mask,
               const float* __restrict__ boxes_sel, const float* __restrict__ scores_sel,
               float* __restrict__ out, int B)
{
    __shared__ int ki[PC];
    const int lane = threadIdx.x;
    const int b = blockIdx.x;
    const u64* mb = mask + (size_t)b * KSEL * NW;

    u64 remv0 = 0, remv1 = 0;          // lane l holds removal words l and 64+l
    int kept = 0;
    u64 mcur = mb[(size_t)lane * NW];  // chunk 0 diagonal word

    for (int c = 0; c < NW; ++c) {
        int rin = (c + 1) * 64 + lane;                       // prefetch next diagonal
        u64 mnext = (c + 1 < NW && rin < KSEL) ? mb[(size_t)rin * NW + (c + 1)] : 0ULL;

        u64 r = (c < 64) ? bcast64(remv0, c) : bcast64(remv1, c - 64);
        int rbn = KSEL - c * 64;
        u64 valid = (rbn >= 64) ? ~0ULL : ((1ULL << rbn) - 1ULL);
        u64 pend = valid & ~r;
        u64 keep = 0;
        while (pend) {                                       // wave-uniform greedy resolve
            int bb = (int)(__ffsll((unsigned long long)pend) - 1);
            keep |= 1ULL << bb;
            u64 sup = bcast64(mcur, bb);
            pend &= ~(sup | (1ULL << bb));
        }
        int m = __popcll((unsigned long long)keep);

        int mybit = 0;                                       // lane q holds q-th kept bit
        {
            u64 kk = keep; int q = 0;
            while (kk) {
                int bb = (int)(__ffsll((unsigned long long)kk) - 1); kk &= kk - 1;
                if (q == lane) mybit = bb;
                if (lane == 0 && kept + q < PC) ki[kept + q] = c * 64 + bb;
                ++q;
            }
        }
        kept += m;
        if (kept >= PC) { kept = PC; break; }
        if (c + 1 == NW) break;

        // OR kept rows into distributed removal mask, 8 rows per batch, named regs
        {
            const int cb = c * 64;
            const bool hiv = (lane < NW - 64);
            int nb8 = (m + 7) >> 3;
            for (int j = 0; j < nb8; ++j) {
                int qb = j * 8;
                int r0 = __builtin_amdgcn_readlane(mybit, qb + 0);
                int r1 = __builtin_amdgcn_readlane(mybit, qb + 1);
                int r2 = __builtin_amdgcn_readlane(mybit, qb + 2);
                int r3 = __builtin_amdgcn_readlane(mybit, qb + 3);
                int r4 = __builtin_amdgcn_readlane(mybit, qb + 4);
                int r5 = __builtin_amdgcn_readlane(mybit, qb + 5);
                int r6 = __builtin_amdgcn_readlane(mybit, qb + 6);
                int r7 = __builtin_amdgcn_readlane(mybit, qb + 7);
                const u64* w0 = mb + (size_t)(cb + r0) * NW;
                const u64* w1 = mb + (size_t)(cb + r1) * NW;
                const u64* w2 = mb + (size_t)(cb + r2) * NW;
                const u64* w3 = mb + (size_t)(cb + r3) * NW;
                const u64* w4 = mb + (size_t)(cb + r4) * NW;
                const u64* w5 = mb + (size_t)(cb + r5) * NW;
                const u64* w6 = mb + (size_t)(cb + r6) * NW;
                const u64* w7 = mb + (size_t)(cb + r7) * NW;
                u64 t0 = w0[lane], h0 = hiv ? w0[64 + lane] : 0ULL;
                u64 t1 = w1[lane], h1 = hiv ? w1[64 + lane] : 0ULL;
                u64 t2 = w2[lane], h2 = hiv ? w2[64 + lane] : 0ULL;
                u64 t3 = w3[lane], h3 = hiv ? w3[64 + lane] : 0ULL;
                u64 t4 = w4[lane], h4 = hiv ? w4[64 + lane] : 0ULL;
                u64 t5 = w5[lane], h5 = hiv ? w5[64 + lane] : 0ULL;
                u64 t6 = w6[lane], h6 = hiv ? w6[64 + lane] : 0ULL;
                u64 t7 = w7[lane], h7 = hiv ? w7[64 + lane] : 0ULL;
                if (qb + 1 >= m) { t1 = 0; h1 = 0; }
                if (qb + 2 >= m) { t2 = 0; h2 = 0; }
                if (qb + 3 >= m) { t3 = 0; h3 = 0; }
                if (qb + 4 >= m) { t4 = 0; h4 = 0; }
                if (qb + 5 >= m) { t5 = 0; h5 = 0; }
                if (qb + 6 >= m) { t6 = 0; h6 = 0; }
                if (qb + 7 >= m) { t7 = 0; h7 = 0; }
                remv0 |= t0 | t1 | t2 | t3 | t4 | t5 | t6 | t7;
                remv1 |= h0 | h1 | h2 | h3 | h4 | h5 | h6 | h7;
            }
        }
        mcur = mnext;
    }

    // ---- fused output: gather kept, normalize, zero tail, write n ----
    const float4* bx = (const float4*)boxes_sel + (size_t)b * KSEL;
    const float*  sc = scores_sel + (size_t)b * KSEL;
    float4* ob = (float4*)(out + (size_t)b * PC * 4);
    float*  os = out + (size_t)B * PC * 4 + (size_t)b * PC;
    for (int s = lane; s < PC; s += 64) {
        float4 v = make_float4(0.f, 0.f, 0.f, 0.f);
        float sv = 0.f;
        if (s < kept) {
            int i = ki[s];
            float4 t = bx[i];
            v = make_float4(t.x * (1.f/1024.f), t.y * (1.f/1024.f),
                            t.z * (1.f/1024.f), t.w * (1.f/1024.f));
            sv = sc[i];
        }
        ob[s] = v;
        os[s] = sv;
    }
    if (lane == 0) out[(size_t)B * PC * 5 + b] = (float)kept;
}

extern "C" void kernel_launch(void* const* d_in, const int* in_sizes, int n_in,
                              void* d_out, int out_size, void* d_ws, size_t ws_size,
                              hipStream_t stream)
{
    const float* probs   = (const float*)d_in[0];
    const float* deltas  = (const float*)d_in[1];
    const float* anchors = (const float*)d_in[2];
    int A = in_sizes[2] / 4;
    int B = in_sizes[0] / (2 * A);

    char* w = (char*)d_ws;
    size_t off = 0;
    // zero region (single tiny memset): hist8a | hist8b | cnt
    u32* hist8a = (u32*)(w + off);     off += (size_t)B * 256 * sizeof(u32);
    u32* hist8b = (u32*)(w + off);     off += (size_t)B * 256 * sizeof(u32);
    u32* cnt    = (u32*)(w + off);     off += (size_t)B * sizeof(u32);
    size_t zero_bytes = off;
    off = (off + 15) & ~(size_t)15;
    u32* keys = (u32*)(w + off);       off += (size_t)B * A * sizeof(u32);
    off = (off + 15) & ~(size_t)15;
    u64* cand = (u64*)(w + off);       off += (size_t)B * CAP * sizeof(u64);
    float* boxes_sel  = (float*)(w + off); off += (size_t)B * KSEL * 4 * sizeof(float);
    float* scores_sel = (float*)(w + off); off += (size_t)B * KSEL * sizeof(float);
    off = (off + 15) & ~(size_t)15;
    u64* mask = (u64*)(w + off);           off += (size_t)B * KSEL * NW * sizeof(u64);

    hipMemsetAsync(hist8a, 0, zero_bytes, stream);

    dim3 gCH((A + CH - 1) / CH, B);
    dim3 gA((A + 255) / 256, B);
    k_keys_hist8<<<gCH, 256, 0, stream>>>(probs, keys, hist8a, A);
    k_hist8b<<<gCH, 256, 0, stream>>>(keys, hist8a, hist8b, A);
    k_collect<<<gA, 256, 0, stream>>>(keys, hist8a, hist8b, cnt, cand, A);
    k_sortdecode<<<B, 1024, 0, stream>>>(probs, deltas, anchors, cand, cnt,
                                         boxes_sel, scores_sel, A);
    k_iou<<<dim3(NW, NW, B), 64, 0, stream>>>(boxes_sel, mask);
    k_nms_out<<<B, 64, 0, stream>>>(mask, boxes_sel, scores_sel, (float*)d_out, B);
}

// Round 9
// 559.099 us; speedup vs baseline: 1.4497x; 1.0303x over previous
//
#include <hip/hip_runtime.h>
#include <stdint.h>

typedef unsigned int u32;
typedef unsigned long long u64;

#define KSEL 6000      // pre_nms_limit
#define PC   1000      // proposal_count
#define NW   94        // ceil(KSEL/64) removal-mask words
#define CAP  8000      // candidate collection cap
#define CH   2048      // elements per histogram block

// broadcast lane `src` (wave-uniform) of a per-lane u64 to all lanes (SGPR result)
__device__ inline u64 bcast64(u64 v, int src) {
    int s = __builtin_amdgcn_readfirstlane(src);
    u32 lo = __builtin_amdgcn_readlane((u32)(v & 0xFFFFFFFFULL), s);
    u32 hi = __builtin_amdgcn_readlane((u32)(v >> 32), s);
    return ((u64)hi << 32) | lo;
}

// suffix-scan pick over a 256-bin histogram (block of 256 threads).
__device__ void pick256(const u32* __restrict__ h, u32 rem_in, u32* s /*LDS >=258*/,
                        u32* out_bin, u32* out_rem)
{
    const int t = threadIdx.x;
    s[t] = h[t];
    __syncthreads();
    for (int off = 1; off < 256; off <<= 1) {
        u32 add = (t + off < 256) ? s[t + off] : 0u;
        __syncthreads();
        s[t] += add;
        __syncthreads();
    }
    u32 suf = s[t];
    u32 sufn = (t < 255) ? s[t + 1] : 0u;
    if (suf >= rem_in && sufn < rem_in) { s[256] = (u32)t; s[257] = rem_in - sufn; }
    __syncthreads();
    *out_bin = s[256];
    *out_rem = s[257];
}

// ---------------- K0: keys + top-8-bit histogram (LDS-privatized) ----------------
__global__ __launch_bounds__(256)
void k_keys_hist8(const float* __restrict__ probs, u32* __restrict__ keys,
                  u32* __restrict__ hist8a, int A)
{
    __shared__ u32 lh[4][256];
    const int tid = threadIdx.x, b = blockIdx.y;
    const int w = tid >> 6;
    for (int q = tid; q < 1024; q += 256) ((u32*)lh)[q] = 0;
    __syncthreads();
    int base = blockIdx.x * CH;
#pragma unroll
    for (int it = 0; it < CH / 256; ++it) {
        int a = base + it * 256 + tid;
        if (a < A) {
            size_t i = (size_t)b * A + a;
            u32 u = __float_as_uint(probs[i * 2 + 1]);
            u = (u & 0x80000000u) ? ~u : (u | 0x80000000u);   // float order -> uint order
            keys[i] = u;
            atomicAdd(&lh[w][u >> 24], 1u);
        }
    }
    __syncthreads();
    u32 s = lh[0][tid] + lh[1][tid] + lh[2][tid] + lh[3][tid];
    if (s) atomicAdd(&hist8a[b * 256 + tid], s);
}

// ---------------- K1: second-8-bit histogram (pick0 recomputed inline) ----------------
__global__ __launch_bounds__(256)
void k_hist8b(const u32* __restrict__ keys, const u32* __restrict__ hist8a,
              u32* __restrict__ hist8b, int A)
{
    __shared__ u32 ps[258];
    __shared__ u32 lh[4][256];
    const int tid = threadIdx.x, b = blockIdx.y;
    const int w = tid >> 6;
    u32 pfxA, remA;
    pick256(hist8a + b * 256, (u32)KSEL, ps, &pfxA, &remA);
    for (int q = tid; q < 1024; q += 256) ((u32*)lh)[q] = 0;
    __syncthreads();
    int base = blockIdx.x * CH;
#pragma unroll
    for (int it = 0; it < CH / 256; ++it) {
        int a = base + it * 256 + tid;
        if (a < A) {
            u32 k = keys[(size_t)b * A + a];
            if ((k >> 24) == pfxA) atomicAdd(&lh[w][(k >> 16) & 0xFFu], 1u);
        }
    }
    __syncthreads();
    u32 s = lh[0][tid] + lh[1][tid] + lh[2][tid] + lh[3][tid];
    if (s) atomicAdd(&hist8b[b * 256 + tid], s);
}

// ---------------- K2: collect (~key,index) for keys >= T ----------------
__global__ __launch_bounds__(256)
void k_collect(const u32* __restrict__ keys, const u32* __restrict__ hist8a,
               const u32* __restrict__ hist8b, u32* __restrict__ cnt,
               u64* __restrict__ cand, int A)
{
    __shared__ u32 ps[258];
    const int b = blockIdx.y;
    u32 pfxA, remA, binB, remB;
    pick256(hist8a + b * 256, (u32)KSEL, ps, &pfxA, &remA);
    pick256(hist8b + b * 256, remA, ps, &binB, &remB);
    const u32 T = ((pfxA << 8) | binB) << 16;   // floor of threshold 16-bit bin
    int a = blockIdx.x * 256 + threadIdx.x;
    if (a >= A) return;
    u32 k = keys[(size_t)b * A + a];
    if (k >= T) {
        u32 pos = atomicAdd(&cnt[b], 1u);
        if (pos < CAP) cand[(size_t)b * CAP + pos] = ((u64)(~k) << 32) | (u32)a;
    }
}

// ---------------- K3: per-sample stable sort + box decode ----------------
__device__ inline int sphys(int i) { return i + (i >> 3); }
#define CSU(a, b) { if (a > b) { u64 _t = a; a = b; b = _t; } }
#define CSD(a, b) { if (b > a) { u64 _t = a; a = b; b = _t; } }
#define CSV(a, b) { if ((a > b) == up) { u64 _t = a; a = b; b = _t; } }

__global__ __launch_bounds__(1024)
void k_sortdecode(const float* __restrict__ probs, const float* __restrict__ deltas,
                  const float* __restrict__ anchors, const u64* __restrict__ cand,
                  const u32* __restrict__ cntg, float* __restrict__ boxes_sel,
                  float* __restrict__ scores_sel, int A)
{
    __shared__ u64 sbuf[9216];                 // 8192 + pad, 72 KiB
    const int tid = threadIdx.x, b = blockIdx.x;
    int cnt = (int)cntg[b]; if (cnt > CAP) cnt = CAP;
    for (int i = tid; i < cnt; i += 1024) sbuf[sphys(i)] = cand[(size_t)b * CAP + i];
    for (int i = cnt + tid; i < 8192; i += 1024) sbuf[sphys(i)] = ~0ULL;
    __syncthreads();

    const int base = tid * 8;
    const int pb = 9 * tid;                    // sphys(base)
    {
        u64 e0 = sbuf[pb+0], e1 = sbuf[pb+1], e2 = sbuf[pb+2], e3 = sbuf[pb+3];
        u64 e4 = sbuf[pb+4], e5 = sbuf[pb+5], e6 = sbuf[pb+6], e7 = sbuf[pb+7];
        CSU(e0,e1); CSD(e2,e3); CSU(e4,e5); CSD(e6,e7);            // kk=2
        CSU(e0,e2); CSU(e1,e3); CSD(e4,e6); CSD(e5,e7);            // kk=4 jj=2
        CSU(e0,e1); CSU(e2,e3); CSD(e4,e5); CSD(e6,e7);            // kk=4 jj=1
        bool up = ((base & 8) == 0);                               // kk=8
        CSV(e0,e4); CSV(e1,e5); CSV(e2,e6); CSV(e3,e7);
        CSV(e0,e2); CSV(e1,e3); CSV(e4,e6); CSV(e5,e7);
        CSV(e0,e1); CSV(e2,e3); CSV(e4,e5); CSV(e6,e7);
        sbuf[pb+0]=e0; sbuf[pb+1]=e1; sbuf[pb+2]=e2; sbuf[pb+3]=e3;
        sbuf[pb+4]=e4; sbuf[pb+5]=e5; sbuf[pb+6]=e6; sbuf[pb+7]=e7;
    }
    __syncthreads();

    for (int kk = 16; kk <= 8192; kk <<= 1) {
        for (int jj = kk >> 1; jj >= 8; jj >>= 1) {
            for (int i = tid; i < 8192; i += 1024) {
                int ixj = i ^ jj;
                if (ixj > i) {
                    u64 x = sbuf[sphys(i)], y = sbuf[sphys(ixj)];
                    bool u2 = ((i & kk) == 0);
                    if ((x > y) == u2) { sbuf[sphys(i)] = y; sbuf[sphys(ixj)] = x; }
                }
            }
            __syncthreads();
        }
        {   // fused jj=4,2,1 in registers
            bool up = ((base & kk) == 0);
            u64 e0 = sbuf[pb+0], e1 = sbuf[pb+1], e2 = sbuf[pb+2], e3 = sbuf[pb+3];
            u64 e4 = sbuf[pb+4], e5 = sbuf[pb+5], e6 = sbuf[pb+6], e7 = sbuf[pb+7];
            CSV(e0,e4); CSV(e1,e5); CSV(e2,e6); CSV(e3,e7);
            CSV(e0,e2); CSV(e1,e3); CSV(e4,e6); CSV(e5,e7);
            CSV(e0,e1); CSV(e2,e3); CSV(e4,e5); CSV(e6,e7);
            sbuf[pb+0]=e0; sbuf[pb+1]=e1; sbuf[pb+2]=e2; sbuf[pb+3]=e3;
            sbuf[pb+4]=e4; sbuf[pb+5]=e5; sbuf[pb+6]=e6; sbuf[pb+7]=e7;
        }
        __syncthreads();
    }

    for (int s = tid; s < KSEL; s += 1024) {
        u64 ck = sbuf[sphys(s)];
        int a = (int)(u32)ck;
        float score = probs[((size_t)b * A + a) * 2 + 1];
        float4 an = ((const float4*)anchors)[a];
        float4 dl = ((const float4*)deltas)[(size_t)b * A + a];
        float h = an.z - an.x, w = an.w - an.y;
        float cy = an.x + 0.5f * h + dl.x * 0.1f * h;
        float cx = an.y + 0.5f * w + dl.y * 0.1f * w;
        h *= expf(dl.z * 0.2f);
        w *= expf(dl.w * 0.2f);
        float y1 = cy - 0.5f * h, x1 = cx - 0.5f * w;
        float y2 = y1 + h,        x2 = x1 + w;
        y1 = fminf(fmaxf(y1, 0.f), 1024.f);
        x1 = fminf(fmaxf(x1, 0.f), 1024.f);
        y2 = fminf(fmaxf(y2, 0.f), 1024.f);
        x2 = fminf(fmaxf(x2, 0.f), 1024.f);
        ((float4*)boxes_sel)[(size_t)b * KSEL + s] = make_float4(y1, x1, y2, x2);
        scores_sel[(size_t)b * KSEL + s] = score;
    }
}

// ---------------- K4: suppression mask matrix (upper triangle only) ----------------
__global__ __launch_bounds__(64)
void k_iou(const float* __restrict__ boxes_sel, u64* __restrict__ mask)
{
    __shared__ float4 rowb[64];
    int t = threadIdx.x;
    int bi = blockIdx.x, bj = blockIdx.y, b = blockIdx.z;
    if (bj < bi) return;
    const float4* boxes = (const float4*)boxes_sel + (size_t)b * KSEL;
    int ri = bi * 64 + t;
    int j  = bj * 64 + t;
    rowb[t] = (ri < KSEL) ? boxes[ri] : make_float4(0.f, 0.f, 0.f, 0.f);
    float4 cb = (j < KSEL) ? boxes[j] : make_float4(0.f, 0.f, 0.f, 0.f);
    float areaC = (cb.z - cb.x) * (cb.w - cb.y);
    __syncthreads();
    u64 myword = 0;
    for (int r = 0; r < 64; ++r) {
        float4 rb = rowb[r];
        float areaR = (rb.z - rb.x) * (rb.w - rb.y);
        float iy1 = fmaxf(rb.x, cb.x), ix1 = fmaxf(rb.y, cb.y);
        float iy2 = fminf(rb.z, cb.z), ix2 = fminf(rb.w, cb.w);
        float inter = fmaxf(iy2 - iy1, 0.f) * fmaxf(ix2 - ix1, 0.f);
        float uni = fmaxf(areaR + areaC - inter, 1e-10f);
        bool sup = (j < KSEL) && (inter > 0.7f * uni);
        u64 word = __ballot(sup ? 1 : 0);
        if (r == t) myword = word;
    }
    if (ri < KSEL) mask[((size_t)b * KSEL + ri) * NW + bj] = myword;
}

// ---------------- K5: greedy NMS (unconditional clustered loads) + fused output ----------------
// All loads are UNCONDITIONAL (no divergent guard -> compiler clusters them, one
// vmcnt wait per 16-row batch). row[64+lane] for lane >= NW-64 reads into the next
// row / 1KiB guard (defined ws memory); the value is masked by himask afterwards.
__global__ __launch_bounds__(64, 1)
void k_nms_out(const u64* __restrict__ mask,
               const float* __restrict__ boxes_sel, const float* __restrict__ scores_sel,
               float* __restrict__ out, int B)
{
    __shared__ int ki[PC];
    const int lane = threadIdx.x;
    const int b = blockIdx.x;
    const u64* mb = mask + (size_t)b * KSEL * NW;
    const u64 himask = (lane < NW - 64) ? ~0ULL : 0ULL;

    u64 remv0 = 0, remv1 = 0;          // lane l holds removal words l and 64+l
    int kept = 0;
    u64 mcur = mb[(size_t)lane * NW];  // chunk 0 diagonal word

    for (int c = 0; c < NW; ++c) {
        int rin = (c + 1) * 64 + lane;                       // prefetch next diagonal
        u64 mnext = (c + 1 < NW && rin < KSEL) ? mb[(size_t)rin * NW + (c + 1)] : 0ULL;

        u64 r = (c < 64) ? bcast64(remv0, c) : bcast64(remv1, c - 64);
        int rbn = KSEL - c * 64;
        u64 valid = (rbn >= 64) ? ~0ULL : ((1ULL << rbn) - 1ULL);
        u64 pend = valid & ~r;
        u64 keep = 0;
        while (pend) {                                       // wave-uniform greedy resolve
            int bb = (int)(__ffsll((unsigned long long)pend) - 1);
            keep |= 1ULL << bb;
            u64 sup = bcast64(mcur, bb);
            pend &= ~(sup | (1ULL << bb));
        }
        int m = __popcll((unsigned long long)keep);

        int mybit = 0;                                       // lane q holds q-th kept bit
        {
            u64 kk = keep; int q = 0;
            while (kk) {
                int bb = (int)(__ffsll((unsigned long long)kk) - 1); kk &= kk - 1;
                if (q == lane) mybit = bb;
                if (lane == 0 && kept + q < PC) ki[kept + q] = c * 64 + bb;
                ++q;
            }
        }
        kept += m;
        if (kept >= PC) { kept = PC; break; }
        if (c + 1 == NW) break;

        // OR kept rows: 16 rows (32 loads) per batch, all unconditional, one wait
        {
            const int cb = c * 64;
            int nb16 = (m + 15) >> 4;
            for (int j = 0; j < nb16; ++j) {
                int qb = j * 16;
                u64 tv[16], hv[16];
#pragma unroll
                for (int q = 0; q < 16; ++q) {
                    int rq = __builtin_amdgcn_readlane(mybit, qb + q);  // uniform lane idx
                    const u64* row = mb + (size_t)(cb + rq) * NW;
                    tv[q] = row[lane];
                    hv[q] = row[64 + lane];      // may read next row/guard; masked below
                }
#pragma unroll
                for (int q = 0; q < 16; ++q) {
                    u64 live = (qb + q < m) ? ~0ULL : 0ULL;
                    remv0 |= tv[q] & live;
                    remv1 |= hv[q] & live & himask;
                }
            }
        }
        mcur = mnext;
    }

    // ---- fused output: gather kept, normalize, zero tail, write n ----
    const float4* bx = (const float4*)boxes_sel + (size_t)b * KSEL;
    const float*  sc = scores_sel + (size_t)b * KSEL;
    float4* ob = (float4*)(out + (size_t)b * PC * 4);
    float*  os = out + (size_t)B * PC * 4 + (size_t)b * PC;
    for (int s = lane; s < PC; s += 64) {
        float4 v = make_float4(0.f, 0.f, 0.f, 0.f);
        float sv = 0.f;
        if (s < kept) {
            int i = ki[s];
            float4 t = bx[i];
            v = make_float4(t.x * (1.f/1024.f), t.y * (1.f/1024.f),
                            t.z * (1.f/1024.f), t.w * (1.f/1024.f));
            sv = sc[i];
        }
        ob[s] = v;
        os[s] = sv;
    }
    if (lane == 0) out[(size_t)B * PC * 5 + b] = (float)kept;
}

extern "C" void kernel_launch(void* const* d_in, const int* in_sizes, int n_in,
                              void* d_out, int out_size, void* d_ws, size_t ws_size,
                              hipStream_t stream)
{
    const float* probs   = (const float*)d_in[0];
    const float* deltas  = (const float*)d_in[1];
    const float* anchors = (const float*)d_in[2];
    int A = in_sizes[2] / 4;
    int B = in_sizes[0] / (2 * A);

    char* w = (char*)d_ws;
    size_t off = 0;
    // zero region (single tiny memset): hist8a | hist8b | cnt
    u32* hist8a = (u32*)(w + off);     off += (size_t)B * 256 * sizeof(u32);
    u32* hist8b = (u32*)(w + off);     off += (size_t)B * 256 * sizeof(u32);
    u32* cnt    = (u32*)(w + off);     off += (size_t)B * sizeof(u32);
    size_t zero_bytes = off;
    off = (off + 15) & ~(size_t)15;
    u32* keys = (u32*)(w + off);       off += (size_t)B * A * sizeof(u32);
    off = (off + 15) & ~(size_t)15;
    u64* cand = (u64*)(w + off);       off += (size_t)B * CAP * sizeof(u64);
    float* boxes_sel  = (float*)(w + off); off += (size_t)B * KSEL * 4 * sizeof(float);
    float* scores_sel = (float*)(w + off); off += (size_t)B * KSEL * sizeof(float);
    off = (off + 15) & ~(size_t)15;
    u64* mask = (u64*)(w + off);           off += (size_t)B * KSEL * NW * sizeof(u64);
    off += 1024;                           // guard: unconditional row[64+lane] overreads

    hipMemsetAsync(hist8a, 0, zero_bytes, stream);

    dim3 gCH((A + CH - 1) / CH, B);
    dim3 gA((A + 255) / 256, B);
    k_keys_hist8<<<gCH, 256, 0, stream>>>(probs, keys, hist8a, A);
    k_hist8b<<<gCH, 256, 0, stream>>>(keys, hist8a, hist8b, A);
    k_collect<<<gA, 256, 0, stream>>>(keys, hist8a, hist8b, cnt, cand, A);
    k_sortdecode<<<B, 1024, 0, stream>>>(probs, deltas, anchors, cand, cnt,
                                         boxes_sel, scores_sel, A);
    k_iou<<<dim3(NW, NW, B), 64, 0, stream>>>(boxes_sel, mask);
    k_nms_out<<<B, 64, 0, stream>>>(mask, boxes_sel, scores_sel, (float*)d_out, B);
}

// Round 10
// 531.411 us; speedup vs baseline: 1.5252x; 1.0521x over previous
//
#include <hip/hip_runtime.h>
#include <stdint.h>

typedef unsigned int u32;
typedef unsigned long long u64;

#define KSEL 6000      // pre_nms_limit
#define PC   1000      // proposal_count
#define NW   94        // ceil(KSEL/64) removal-mask words
#define CAP  8000      // candidate collection cap
#define CH   2048      // elements per histogram block

// broadcast lane `src` (wave-uniform) of a per-lane u64 to all lanes (SGPR result)
__device__ inline u64 bcast64(u64 v, int src) {
    int s = __builtin_amdgcn_readfirstlane(src);
    u32 lo = __builtin_amdgcn_readlane((u32)(v & 0xFFFFFFFFULL), s);
    u32 hi = __builtin_amdgcn_readlane((u32)(v >> 32), s);
    return ((u64)hi << 32) | lo;
}

// position of q-th (0-indexed) set bit of v; valid when q < popcount(v)
__device__ inline int selbit64(u64 v, int q) {
    int pos = 0;
    u32 x = (u32)v;
    int c = __popc(x);
    if (q >= c) { q -= c; pos = 32; x = (u32)(v >> 32); }
    c = __popc(x & 0xFFFFu);
    if (q >= c) { q -= c; pos += 16; x >>= 16; }
    c = __popc(x & 0xFFu);
    if (q >= c) { q -= c; pos += 8; x >>= 8; }
    c = __popc(x & 0xFu);
    if (q >= c) { q -= c; pos += 4; x >>= 4; }
    c = __popc(x & 0x3u);
    if (q >= c) { q -= c; pos += 2; x >>= 2; }
    c = (int)(x & 1u);
    if (q >= c) pos += 1;
    return pos;
}

// suffix-scan pick over a 256-bin histogram (block of 256 threads).
__device__ void pick256(const u32* __restrict__ h, u32 rem_in, u32* s /*LDS >=258*/,
                        u32* out_bin, u32* out_rem)
{
    const int t = threadIdx.x;
    s[t] = h[t];
    __syncthreads();
    for (int off = 1; off < 256; off <<= 1) {
        u32 add = (t + off < 256) ? s[t + off] : 0u;
        __syncthreads();
        s[t] += add;
        __syncthreads();
    }
    u32 suf = s[t];
    u32 sufn = (t < 255) ? s[t + 1] : 0u;
    if (suf >= rem_in && sufn < rem_in) { s[256] = (u32)t; s[257] = rem_in - sufn; }
    __syncthreads();
    *out_bin = s[256];
    *out_rem = s[257];
}

// ---------------- K0: keys + top-8-bit histogram (LDS-privatized) ----------------
__global__ __launch_bounds__(256)
void k_keys_hist8(const float* __restrict__ probs, u32* __restrict__ keys,
                  u32* __restrict__ hist8a, int A)
{
    __shared__ u32 lh[4][256];
    const int tid = threadIdx.x, b = blockIdx.y;
    const int w = tid >> 6;
    for (int q = tid; q < 1024; q += 256) ((u32*)lh)[q] = 0;
    __syncthreads();
    int base = blockIdx.x * CH;
#pragma unroll
    for (int it = 0; it < CH / 256; ++it) {
        int a = base + it * 256 + tid;
        if (a < A) {
            size_t i = (size_t)b * A + a;
            u32 u = __float_as_uint(probs[i * 2 + 1]);
            u = (u & 0x80000000u) ? ~u : (u | 0x80000000u);   // float order -> uint order
            keys[i] = u;
            atomicAdd(&lh[w][u >> 24], 1u);
        }
    }
    __syncthreads();
    u32 s = lh[0][tid] + lh[1][tid] + lh[2][tid] + lh[3][tid];
    if (s) atomicAdd(&hist8a[b * 256 + tid], s);
}

// ---------------- K1: second-8-bit histogram (pick0 recomputed inline) ----------------
__global__ __launch_bounds__(256)
void k_hist8b(const u32* __restrict__ keys, const u32* __restrict__ hist8a,
              u32* __restrict__ hist8b, int A)
{
    __shared__ u32 ps[258];
    __shared__ u32 lh[4][256];
    const int tid = threadIdx.x, b = blockIdx.y;
    const int w = tid >> 6;
    u32 pfxA, remA;
    pick256(hist8a + b * 256, (u32)KSEL, ps, &pfxA, &remA);
    for (int q = tid; q < 1024; q += 256) ((u32*)lh)[q] = 0;
    __syncthreads();
    int base = blockIdx.x * CH;
#pragma unroll
    for (int it = 0; it < CH / 256; ++it) {
        int a = base + it * 256 + tid;
        if (a < A) {
            u32 k = keys[(size_t)b * A + a];
            if ((k >> 24) == pfxA) atomicAdd(&lh[w][(k >> 16) & 0xFFu], 1u);
        }
    }
    __syncthreads();
    u32 s = lh[0][tid] + lh[1][tid] + lh[2][tid] + lh[3][tid];
    if (s) atomicAdd(&hist8b[b * 256 + tid], s);
}

// ---------------- K2: collect (~key,index) for keys >= T ----------------
__global__ __launch_bounds__(256)
void k_collect(const u32* __restrict__ keys, const u32* __restrict__ hist8a,
               const u32* __restrict__ hist8b, u32* __restrict__ cnt,
               u64* __restrict__ cand, int A)
{
    __shared__ u32 ps[258];
    const int b = blockIdx.y;
    u32 pfxA, remA, binB, remB;
    pick256(hist8a + b * 256, (u32)KSEL, ps, &pfxA, &remA);
    pick256(hist8b + b * 256, remA, ps, &binB, &remB);
    const u32 T = ((pfxA << 8) | binB) << 16;   // floor of threshold 16-bit bin
    int a = blockIdx.x * 256 + threadIdx.x;
    if (a >= A) return;
    u32 k = keys[(size_t)b * A + a];
    if (k >= T) {
        u32 pos = atomicAdd(&cnt[b], 1u);
        if (pos < CAP) cand[(size_t)b * CAP + pos] = ((u64)(~k) << 32) | (u32)a;
    }
}

// ---------------- K3: per-sample stable sort + box decode ----------------
__device__ inline int sphys(int i) { return i + (i >> 3); }
#define CSU(a, b) { if (a > b) { u64 _t = a; a = b; b = _t; } }
#define CSD(a, b) { if (b > a) { u64 _t = a; a = b; b = _t; } }
#define CSV(a, b) { if ((a > b) == up) { u64 _t = a; a = b; b = _t; } }

__global__ __launch_bounds__(1024)
void k_sortdecode(const float* __restrict__ probs, const float* __restrict__ deltas,
                  const float* __restrict__ anchors, const u64* __restrict__ cand,
                  const u32* __restrict__ cntg, float* __restrict__ boxes_sel,
                  float* __restrict__ scores_sel, int A)
{
    __shared__ u64 sbuf[9216];                 // 8192 + pad, 72 KiB
    const int tid = threadIdx.x, b = blockIdx.x;
    int cnt = (int)cntg[b]; if (cnt > CAP) cnt = CAP;
    for (int i = tid; i < cnt; i += 1024) sbuf[sphys(i)] = cand[(size_t)b * CAP + i];
    for (int i = cnt + tid; i < 8192; i += 1024) sbuf[sphys(i)] = ~0ULL;
    __syncthreads();

    const int base = tid * 8;
    const int pb = 9 * tid;                    // sphys(base)
    {
        u64 e0 = sbuf[pb+0], e1 = sbuf[pb+1], e2 = sbuf[pb+2], e3 = sbuf[pb+3];
        u64 e4 = sbuf[pb+4], e5 = sbuf[pb+5], e6 = sbuf[pb+6], e7 = sbuf[pb+7];
        CSU(e0,e1); CSD(e2,e3); CSU(e4,e5); CSD(e6,e7);            // kk=2
        CSU(e0,e2); CSU(e1,e3); CSD(e4,e6); CSD(e5,e7);            // kk=4 jj=2
        CSU(e0,e1); CSU(e2,e3); CSD(e4,e5); CSD(e6,e7);            // kk=4 jj=1
        bool up = ((base & 8) == 0);                               // kk=8
        CSV(e0,e4); CSV(e1,e5); CSV(e2,e6); CSV(e3,e7);
        CSV(e0,e2); CSV(e1,e3); CSV(e4,e6); CSV(e5,e7);
        CSV(e0,e1); CSV(e2,e3); CSV(e4,e5); CSV(e6,e7);
        sbuf[pb+0]=e0; sbuf[pb+1]=e1; sbuf[pb+2]=e2; sbuf[pb+3]=e3;
        sbuf[pb+4]=e4; sbuf[pb+5]=e5; sbuf[pb+6]=e6; sbuf[pb+7]=e7;
    }
    __syncthreads();

    for (int kk = 16; kk <= 8192; kk <<= 1) {
        for (int jj = kk >> 1; jj >= 8; jj >>= 1) {
            for (int i = tid; i < 8192; i += 1024) {
                int ixj = i ^ jj;
                if (ixj > i) {
                    u64 x = sbuf[sphys(i)], y = sbuf[sphys(ixj)];
                    bool u2 = ((i & kk) == 0);
                    if ((x > y) == u2) { sbuf[sphys(i)] = y; sbuf[sphys(ixj)] = x; }
                }
            }
            __syncthreads();
        }
        {   // fused jj=4,2,1 in registers
            bool up = ((base & kk) == 0);
            u64 e0 = sbuf[pb+0], e1 = sbuf[pb+1], e2 = sbuf[pb+2], e3 = sbuf[pb+3];
            u64 e4 = sbuf[pb+4], e5 = sbuf[pb+5], e6 = sbuf[pb+6], e7 = sbuf[pb+7];
            CSV(e0,e4); CSV(e1,e5); CSV(e2,e6); CSV(e3,e7);
            CSV(e0,e2); CSV(e1,e3); CSV(e4,e6); CSV(e5,e7);
            CSV(e0,e1); CSV(e2,e3); CSV(e4,e5); CSV(e6,e7);
            sbuf[pb+0]=e0; sbuf[pb+1]=e1; sbuf[pb+2]=e2; sbuf[pb+3]=e3;
            sbuf[pb+4]=e4; sbuf[pb+5]=e5; sbuf[pb+6]=e6; sbuf[pb+7]=e7;
        }
        __syncthreads();
    }

    for (int s = tid; s < KSEL; s += 1024) {
        u64 ck = sbuf[sphys(s)];
        int a = (int)(u32)ck;
        float score = probs[((size_t)b * A + a) * 2 + 1];
        float4 an = ((const float4*)anchors)[a];
        float4 dl = ((const float4*)deltas)[(size_t)b * A + a];
        float h = an.z - an.x, w = an.w - an.y;
        float cy = an.x + 0.5f * h + dl.x * 0.1f * h;
        float cx = an.y + 0.5f * w + dl.y * 0.1f * w;
        h *= expf(dl.z * 0.2f);
        w *= expf(dl.w * 0.2f);
        float y1 = cy - 0.5f * h, x1 = cx - 0.5f * w;
        float y2 = y1 + h,        x2 = x1 + w;
        y1 = fminf(fmaxf(y1, 0.f), 1024.f);
        x1 = fminf(fmaxf(x1, 0.f), 1024.f);
        y2 = fminf(fmaxf(y2, 0.f), 1024.f);
        x2 = fminf(fmaxf(x2, 0.f), 1024.f);
        ((float4*)boxes_sel)[(size_t)b * KSEL + s] = make_float4(y1, x1, y2, x2);
        scores_sel[(size_t)b * KSEL + s] = score;
    }
}

// ---------------- K4: suppression mask matrix (upper triangle only) ----------------
__global__ __launch_bounds__(64)
void k_iou(const float* __restrict__ boxes_sel, u64* __restrict__ mask)
{
    __shared__ float4 rowb[64];
    int t = threadIdx.x;
    int bi = blockIdx.x, bj = blockIdx.y, b = blockIdx.z;
    if (bj < bi) return;
    const float4* boxes = (const float4*)boxes_sel + (size_t)b * KSEL;
    int ri = bi * 64 + t;
    int j  = bj * 64 + t;
    rowb[t] = (ri < KSEL) ? boxes[ri] : make_float4(0.f, 0.f, 0.f, 0.f);
    float4 cb = (j < KSEL) ? boxes[j] : make_float4(0.f, 0.f, 0.f, 0.f);
    float areaC = (cb.z - cb.x) * (cb.w - cb.y);
    __syncthreads();
    u64 myword = 0;
    for (int r = 0; r < 64; ++r) {
        float4 rb = rowb[r];
        float areaR = (rb.z - rb.x) * (rb.w - rb.y);
        float iy1 = fmaxf(rb.x, cb.x), ix1 = fmaxf(rb.y, cb.y);
        float iy2 = fminf(rb.z, cb.z), ix2 = fminf(rb.w, cb.w);
        float inter = fmaxf(iy2 - iy1, 0.f) * fmaxf(ix2 - ix1, 0.f);
        float uni = fmaxf(areaR + areaC - inter, 1e-10f);
        bool sup = (j < KSEL) && (inter > 0.7f * uni);
        u64 word = __ballot(sup ? 1 : 0);
        if (r == t) myword = word;
    }
    if (ri < KSEL) mask[((size_t)b * KSEL + ri) * NW + bj] = myword;
}

// ---------------- K5: greedy NMS (asm-clustered dwordx4 row loads) + fused output ----------------
// Paired-word removal state: lane l holds words 2l (remvA) and 2l+1 (remvB), so a
// full 94-word mask row is ONE 16B-aligned global_load_dwordx4 per lane (752 = 47*16).
// 8 rows per asm block: loads provably back-to-back, single s_waitcnt -> 1 round trip.
__global__ __launch_bounds__(64, 1)
void k_nms_out(const u64* __restrict__ mask,
               const float* __restrict__ boxes_sel, const float* __restrict__ scores_sel,
               float* __restrict__ out, int B)
{
    __shared__ int ki[PC];
    const int lane = threadIdx.x;
    const int b = blockIdx.x;
    const u64* mb = mask + (size_t)b * KSEL * NW;
    const u64 wmA = (2 * lane     < NW) ? ~0ULL : 0ULL;
    const u64 wmB = (2 * lane + 1 < NW) ? ~0ULL : 0ULL;

    u64 remvA = 0, remvB = 0;          // lane l: removal words 2l, 2l+1
    int kept = 0;
    u64 mcur = mb[(size_t)lane * NW];  // chunk 0 diagonal word

    for (int c = 0; c < NW; ++c) {
        int rin = (c + 1) * 64 + lane;                       // prefetch next diagonal
        u64 mnext = (c + 1 < NW && rin < KSEL) ? mb[(size_t)rin * NW + (c + 1)] : 0ULL;

        u64 r = (c & 1) ? bcast64(remvB, c >> 1) : bcast64(remvA, c >> 1);
        int rbn = KSEL - c * 64;
        u64 valid = (rbn >= 64) ? ~0ULL : ((1ULL << rbn) - 1ULL);
        u64 pend = valid & ~r;
        u64 keep = 0;
        while (pend) {                                       // wave-uniform greedy resolve
            int bb = (int)(__ffsll((unsigned long long)pend) - 1);
            keep |= 1ULL << bb;
            u64 sup = bcast64(mcur, bb);
            pend &= ~(sup | (1ULL << bb));
        }
        int m = __popcll((unsigned long long)keep);
        int mybit = selbit64(keep, lane);                    // lane q -> q-th kept bit
        if (lane < m && kept + lane < PC) ki[kept + lane] = c * 64 + mybit;
        kept += m;
        if (kept >= PC) { kept = PC; break; }
        if (c + 1 == NW) break;

        if (m) {
            const int cbase = c * 64;
            const int mm = m - 1;
            int nb8 = (m + 7) >> 3;
            for (int j = 0; j < nb8; ++j) {
                int qb = j * 8;
                int i0 = qb     > mm ? mm : qb;
                int i1 = qb + 1 > mm ? mm : qb + 1;
                int i2 = qb + 2 > mm ? mm : qb + 2;
                int i3 = qb + 3 > mm ? mm : qb + 3;
                int i4 = qb + 4 > mm ? mm : qb + 4;
                int i5 = qb + 5 > mm ? mm : qb + 5;
                int i6 = qb + 6 > mm ? mm : qb + 6;
                int i7 = qb + 7 > mm ? mm : qb + 7;
                int r0 = __builtin_amdgcn_readlane(mybit, i0);
                int r1 = __builtin_amdgcn_readlane(mybit, i1);
                int r2 = __builtin_amdgcn_readlane(mybit, i2);
                int r3 = __builtin_amdgcn_readlane(mybit, i3);
                int r4 = __builtin_amdgcn_readlane(mybit, i4);
                int r5 = __builtin_amdgcn_readlane(mybit, i5);
                int r6 = __builtin_amdgcn_readlane(mybit, i6);
                int r7 = __builtin_amdgcn_readlane(mybit, i7);
                const u64* p0 = mb + (size_t)(cbase + r0) * NW + 2 * lane;
                const u64* p1 = mb + (size_t)(cbase + r1) * NW + 2 * lane;
                const u64* p2 = mb + (size_t)(cbase + r2) * NW + 2 * lane;
                const u64* p3 = mb + (size_t)(cbase + r3) * NW + 2 * lane;
                const u64* p4 = mb + (size_t)(cbase + r4) * NW + 2 * lane;
                const u64* p5 = mb + (size_t)(cbase + r5) * NW + 2 * lane;
                const u64* p6 = mb + (size_t)(cbase + r6) * NW + 2 * lane;
                const u64* p7 = mb + (size_t)(cbase + r7) * NW + 2 * lane;
                int4 d0, d1, d2, d3, d4, d5, d6, d7;
                asm volatile(
                    "global_load_dwordx4 %0, %8, off\n\t"
                    "global_load_dwordx4 %1, %9, off\n\t"
                    "global_load_dwordx4 %2, %10, off\n\t"
                    "global_load_dwordx4 %3, %11, off\n\t"
                    "global_load_dwordx4 %4, %12, off\n\t"
                    "global_load_dwordx4 %5, %13, off\n\t"
                    "global_load_dwordx4 %6, %14, off\n\t"
                    "global_load_dwordx4 %7, %15, off\n\t"
                    "s_waitcnt vmcnt(0)"
                    : "=&v"(d0), "=&v"(d1), "=&v"(d2), "=&v"(d3),
                      "=&v"(d4), "=&v"(d5), "=&v"(d6), "=&v"(d7)
                    : "v"(p0), "v"(p1), "v"(p2), "v"(p3),
                      "v"(p4), "v"(p5), "v"(p6), "v"(p7)
                    : "memory");
                u64 aacc = 0, bacc = 0;
                u64 lo, hi, live;
                live = (qb + 0 < m) ? ~0ULL : 0ULL;
                lo = ((u64)(u32)d0.y << 32) | (u32)d0.x;
                hi = ((u64)(u32)d0.w << 32) | (u32)d0.z;
                aacc |= lo & live; bacc |= hi & live;
                live = (qb + 1 < m) ? ~0ULL : 0ULL;
                lo = ((u64)(u32)d1.y << 32) | (u32)d1.x;
                hi = ((u64)(u32)d1.w << 32) | (u32)d1.z;
                aacc |= lo & live; bacc |= hi & live;
                live = (qb + 2 < m) ? ~0ULL : 0ULL;
                lo = ((u64)(u32)d2.y << 32) | (u32)d2.x;
                hi = ((u64)(u32)d2.w << 32) | (u32)d2.z;
                aacc |= lo & live; bacc |= hi & live;
                live = (qb + 3 < m) ? ~0ULL : 0ULL;
                lo = ((u64)(u32)d3.y << 32) | (u32)d3.x;
                hi = ((u64)(u32)d3.w << 32) | (u32)d3.z;
                aacc |= lo & live; bacc |= hi & live;
                live = (qb + 4 < m) ? ~0ULL : 0ULL;
                lo = ((u64)(u32)d4.y << 32) | (u32)d4.x;
                hi = ((u64)(u32)d4.w << 32) | (u32)d4.z;
                aacc |= lo & live; bacc |= hi & live;
                live = (qb + 5 < m) ? ~0ULL : 0ULL;
                lo = ((u64)(u32)d5.y << 32) | (u32)d5.x;
                hi = ((u64)(u32)d5.w << 32) | (u32)d5.z;
                aacc |= lo & live; bacc |= hi & live;
                live = (qb + 6 < m) ? ~0ULL : 0ULL;
                lo = ((u64)(u32)d6.y << 32) | (u32)d6.x;
                hi = ((u64)(u32)d6.w << 32) | (u32)d6.z;
                aacc |= lo & live; bacc |= hi & live;
                live = (qb + 7 < m) ? ~0ULL : 0ULL;
                lo = ((u64)(u32)d7.y << 32) | (u32)d7.x;
                hi = ((u64)(u32)d7.w << 32) | (u32)d7.z;
                aacc |= lo & live; bacc |= hi & live;
                remvA |= aacc & wmA;
                remvB |= bacc & wmB;
            }
        }
        mcur = mnext;
    }

    // ---- fused output: gather kept, normalize, zero tail, write n ----
    const float4* bx = (const float4*)boxes_sel + (size_t)b * KSEL;
    const float*  sc = scores_sel + (size_t)b * KSEL;
    float4* ob = (float4*)(out + (size_t)b * PC * 4);
    float*  os = out + (size_t)B * PC * 4 + (size_t)b * PC;
    for (int s = lane; s < PC; s += 64) {
        float4 v = make_float4(0.f, 0.f, 0.f, 0.f);
        float sv = 0.f;
        if (s < kept) {
            int i = ki[s];
            float4 t = bx[i];
            v = make_float4(t.x * (1.f/1024.f), t.y * (1.f/1024.f),
                            t.z * (1.f/1024.f), t.w * (1.f/1024.f));
            sv = sc[i];
        }
        ob[s] = v;
        os[s] = sv;
    }
    if (lane == 0) out[(size_t)B * PC * 5 + b] = (float)kept;
}

extern "C" void kernel_launch(void* const* d_in, const int* in_sizes, int n_in,
                              void* d_out, int out_size, void* d_ws, size_t ws_size,
                              hipStream_t stream)
{
    const float* probs   = (const float*)d_in[0];
    const float* deltas  = (const float*)d_in[1];
    const float* anchors = (const float*)d_in[2];
    int A = in_sizes[2] / 4;
    int B = in_sizes[0] / (2 * A);

    char* w = (char*)d_ws;
    size_t off = 0;
    // zero region (single tiny memset): hist8a | hist8b | cnt
    u32* hist8a = (u32*)(w + off);     off += (size_t)B * 256 * sizeof(u32);
    u32* hist8b = (u32*)(w + off);     off += (size_t)B * 256 * sizeof(u32);
    u32* cnt    = (u32*)(w + off);     off += (size_t)B * sizeof(u32);
    size_t zero_bytes = off;
    off = (off + 15) & ~(size_t)15;
    u32* keys = (u32*)(w + off);       off += (size_t)B * A * sizeof(u32);
    off = (off + 15) & ~(size_t)15;
    u64* cand = (u64*)(w + off);       off += (size_t)B * CAP * sizeof(u64);
    float* boxes_sel  = (float*)(w + off); off += (size_t)B * KSEL * 4 * sizeof(float);
    float* scores_sel = (float*)(w + off); off += (size_t)B * KSEL * sizeof(float);
    off = (off + 15) & ~(size_t)15;
    u64* mask = (u64*)(w + off);           off += (size_t)B * KSEL * NW * sizeof(u64);
    off += 1024;                           // guard: dwordx4 row loads overread past word 93

    hipMemsetAsync(hist8a, 0, zero_bytes, stream);

    dim3 gCH((A + CH - 1) / CH, B);
    dim3 gA((A + 255) / 256, B);
    k_keys_hist8<<<gCH, 256, 0, stream>>>(probs, keys, hist8a, A);
    k_hist8b<<<gCH, 256, 0, stream>>>(keys, hist8a, hist8b, A);
    k_collect<<<gA, 256, 0, stream>>>(keys, hist8a, hist8b, cnt, cand, A);
    k_sortdecode<<<B, 1024, 0, stream>>>(probs, deltas, anchors, cand, cnt,
                                         boxes_sel, scores_sel, A);
    k_iou<<<dim3(NW, NW, B), 64, 0, stream>>>(boxes_sel, mask);
    k_nms_out<<<B, 64, 0, stream>>>(mask, boxes_sel, scores_sel, (float*)d_out, B);
}

// Round 13
// 426.259 us; speedup vs baseline: 1.9014x; 1.2467x over previous
//
#include <hip/hip_runtime.h>
#include <stdint.h>

typedef unsigned int u32;
typedef unsigned long long u64;

#define KSEL 6000      // pre_nms_limit
#define PC   1000      // proposal_count
#define NW   94        // ceil(KSEL/64) removal-mask words
#define CAP  8000      // candidate collection cap
#define CH   2048      // elements per histogram block

// broadcast lane `src` (wave-uniform) of a per-lane u64 to all lanes (SGPR result)
__device__ inline u64 bcast64(u64 v, int src) {
    int s = __builtin_amdgcn_readfirstlane(src);
    u32 lo = __builtin_amdgcn_readlane((u32)(v & 0xFFFFFFFFULL), s);
    u32 hi = __builtin_amdgcn_readlane((u32)(v >> 32), s);
    return ((u64)hi << 32) | lo;
}

// position of q-th (0-indexed) set bit of v; valid when q < popcount(v)
__device__ inline int selbit64(u64 v, int q) {
    int pos = 0;
    u32 x = (u32)v;
    int c = __popc(x);
    if (q >= c) { q -= c; pos = 32; x = (u32)(v >> 32); }
    c = __popc(x & 0xFFFFu);
    if (q >= c) { q -= c; pos += 16; x >>= 16; }
    c = __popc(x & 0xFFu);
    if (q >= c) { q -= c; pos += 8; x >>= 8; }
    c = __popc(x & 0xFu);
    if (q >= c) { q -= c; pos += 4; x >>= 4; }
    c = __popc(x & 0x3u);
    if (q >= c) { q -= c; pos += 2; x >>= 2; }
    c = (int)(x & 1u);
    if (q >= c) pos += 1;
    return pos;
}

// suffix-scan pick over a 256-bin histogram (block of 256 threads).
__device__ void pick256(const u32* __restrict__ h, u32 rem_in, u32* s /*LDS >=258*/,
                        u32* out_bin, u32* out_rem)
{
    const int t = threadIdx.x;
    s[t] = h[t];
    __syncthreads();
    for (int off = 1; off < 256; off <<= 1) {
        u32 add = (t + off < 256) ? s[t + off] : 0u;
        __syncthreads();
        s[t] += add;
        __syncthreads();
    }
    u32 suf = s[t];
    u32 sufn = (t < 255) ? s[t + 1] : 0u;
    if (suf >= rem_in && sufn < rem_in) { s[256] = (u32)t; s[257] = rem_in - sufn; }
    __syncthreads();
    *out_bin = s[256];
    *out_rem = s[257];
}

// ---------------- K0: keys + top-8-bit histogram (LDS-privatized) ----------------
__global__ __launch_bounds__(256)
void k_keys_hist8(const float* __restrict__ probs, u32* __restrict__ keys,
                  u32* __restrict__ hist8a, int A)
{
    __shared__ u32 lh[4][256];
    const int tid = threadIdx.x, b = blockIdx.y;
    const int w = tid >> 6;
    for (int q = tid; q < 1024; q += 256) ((u32*)lh)[q] = 0;
    __syncthreads();
    int base = blockIdx.x * CH;
#pragma unroll
    for (int it = 0; it < CH / 256; ++it) {
        int a = base + it * 256 + tid;
        if (a < A) {
            size_t i = (size_t)b * A + a;
            u32 u = __float_as_uint(probs[i * 2 + 1]);
            u = (u & 0x80000000u) ? ~u : (u | 0x80000000u);   // float order -> uint order
            keys[i] = u;
            atomicAdd(&lh[w][u >> 24], 1u);
        }
    }
    __syncthreads();
    u32 s = lh[0][tid] + lh[1][tid] + lh[2][tid] + lh[3][tid];
    if (s) atomicAdd(&hist8a[b * 256 + tid], s);
}

// ---------------- K1: second-8-bit histogram (pick0 recomputed inline) ----------------
__global__ __launch_bounds__(256)
void k_hist8b(const u32* __restrict__ keys, const u32* __restrict__ hist8a,
              u32* __restrict__ hist8b, int A)
{
    __shared__ u32 ps[258];
    __shared__ u32 lh[4][256];
    const int tid = threadIdx.x, b = blockIdx.y;
    const int w = tid >> 6;
    u32 pfxA, remA;
    pick256(hist8a + b * 256, (u32)KSEL, ps, &pfxA, &remA);
    for (int q = tid; q < 1024; q += 256) ((u32*)lh)[q] = 0;
    __syncthreads();
    int base = blockIdx.x * CH;
#pragma unroll
    for (int it = 0; it < CH / 256; ++it) {
        int a = base + it * 256 + tid;
        if (a < A) {
            u32 k = keys[(size_t)b * A + a];
            if ((k >> 24) == pfxA) atomicAdd(&lh[w][(k >> 16) & 0xFFu], 1u);
        }
    }
    __syncthreads();
    u32 s = lh[0][tid] + lh[1][tid] + lh[2][tid] + lh[3][tid];
    if (s) atomicAdd(&hist8b[b * 256 + tid], s);
}

// ---------------- K2: collect (~key,index), wave-aggregated block atomic ----------------
// cand order is irrelevant (sorted later) -> ballot-aggregate: ONE atomicAdd per
// block (was one per passing thread: 6400 same-address atomics -> 153us, G12).
__global__ __launch_bounds__(256)
void k_collect(const u32* __restrict__ keys, const u32* __restrict__ hist8a,
               const u32* __restrict__ hist8b, u32* __restrict__ cnt,
               u64* __restrict__ cand, int A)
{
    __shared__ u32 ps[258];
    __shared__ u32 wb[4];
    const int b = blockIdx.y;
    const int tid = threadIdx.x;
    u32 pfxA, remA, binB, remB;
    pick256(hist8a + b * 256, (u32)KSEL, ps, &pfxA, &remA);
    pick256(hist8b + b * 256, remA, ps, &binB, &remB);
    const u32 T = ((pfxA << 8) | binB) << 16;   // floor of threshold 16-bit bin

    int a = blockIdx.x * 256 + tid;
    u32 k = 0;
    bool pred = false;
    if (a < A) { k = keys[(size_t)b * A + a]; pred = (k >= T); }

    u64 bal = __ballot(pred ? 1 : 0);
    int wid = tid >> 6, lane = tid & 63;
    if (lane == 0) wb[wid] = (u32)__popcll((unsigned long long)bal);
    __syncthreads();
    if (tid == 0) {
        u32 c0 = wb[0], c1 = wb[1], c2 = wb[2], c3 = wb[3];
        u32 tot = c0 + c1 + c2 + c3;
        u32 base = tot ? atomicAdd(&cnt[b], tot) : 0u;
        wb[0] = base; wb[1] = base + c0; wb[2] = base + c0 + c1; wb[3] = base + c0 + c1 + c2;
    }
    __syncthreads();
    if (pred) {
        u32 rank = (u32)__popcll((unsigned long long)(bal & ((lane == 63) ? ~0ULL >> 1 : ((1ULL << lane) - 1))));
        u32 pos = wb[wid] + rank;
        if (pos < CAP) cand[(size_t)b * CAP + pos] = ((u64)(~k) << 32) | (u32)a;
    }
}

// ---------------- K3: per-sample stable sort + box decode ----------------
__device__ inline int sphys(int i) { return i + (i >> 3); }
#define CSU(a, b) { if (a > b) { u64 _t = a; a = b; b = _t; } }
#define CSD(a, b) { if (b > a) { u64 _t = a; a = b; b = _t; } }
#define CSV(a, b) { if ((a > b) == up) { u64 _t = a; a = b; b = _t; } }

__global__ __launch_bounds__(1024)
void k_sortdecode(const float* __restrict__ probs, const float* __restrict__ deltas,
                  const float* __restrict__ anchors, const u64* __restrict__ cand,
                  const u32* __restrict__ cntg, float* __restrict__ boxes_sel,
                  float* __restrict__ scores_sel, int A)
{
    __shared__ u64 sbuf[9216];                 // 8192 + pad, 72 KiB
    const int tid = threadIdx.x, b = blockIdx.x;
    int cnt = (int)cntg[b]; if (cnt > CAP) cnt = CAP;
    for (int i = tid; i < cnt; i += 1024) sbuf[sphys(i)] = cand[(size_t)b * CAP + i];
    for (int i = cnt + tid; i < 8192; i += 1024) sbuf[sphys(i)] = ~0ULL;
    __syncthreads();

    const int base = tid * 8;
    const int pb = 9 * tid;                    // sphys(base)
    {
        u64 e0 = sbuf[pb+0], e1 = sbuf[pb+1], e2 = sbuf[pb+2], e3 = sbuf[pb+3];
        u64 e4 = sbuf[pb+4], e5 = sbuf[pb+5], e6 = sbuf[pb+6], e7 = sbuf[pb+7];
        CSU(e0,e1); CSD(e2,e3); CSU(e4,e5); CSD(e6,e7);            // kk=2
        CSU(e0,e2); CSU(e1,e3); CSD(e4,e6); CSD(e5,e7);            // kk=4 jj=2
        CSU(e0,e1); CSU(e2,e3); CSD(e4,e5); CSD(e6,e7);            // kk=4 jj=1
        bool up = ((base & 8) == 0);                               // kk=8
        CSV(e0,e4); CSV(e1,e5); CSV(e2,e6); CSV(e3,e7);
        CSV(e0,e2); CSV(e1,e3); CSV(e4,e6); CSV(e5,e7);
        CSV(e0,e1); CSV(e2,e3); CSV(e4,e5); CSV(e6,e7);
        sbuf[pb+0]=e0; sbuf[pb+1]=e1; sbuf[pb+2]=e2; sbuf[pb+3]=e3;
        sbuf[pb+4]=e4; sbuf[pb+5]=e5; sbuf[pb+6]=e6; sbuf[pb+7]=e7;
    }
    __syncthreads();

    for (int kk = 16; kk <= 8192; kk <<= 1) {
        for (int jj = kk >> 1; jj >= 8; jj >>= 1) {
            for (int i = tid; i < 8192; i += 1024) {
                int ixj = i ^ jj;
                if (ixj > i) {
                    u64 x = sbuf[sphys(i)], y = sbuf[sphys(ixj)];
                    bool u2 = ((i & kk) == 0);
                    if ((x > y) == u2) { sbuf[sphys(i)] = y; sbuf[sphys(ixj)] = x; }
                }
            }
            __syncthreads();
        }
        {   // fused jj=4,2,1 in registers
            bool up = ((base & kk) == 0);
            u64 e0 = sbuf[pb+0], e1 = sbuf[pb+1], e2 = sbuf[pb+2], e3 = sbuf[pb+3];
            u64 e4 = sbuf[pb+4], e5 = sbuf[pb+5], e6 = sbuf[pb+6], e7 = sbuf[pb+7];
            CSV(e0,e4); CSV(e1,e5); CSV(e2,e6); CSV(e3,e7);
            CSV(e0,e2); CSV(e1,e3); CSV(e4,e6); CSV(e5,e7);
            CSV(e0,e1); CSV(e2,e3); CSV(e4,e5); CSV(e6,e7);
            sbuf[pb+0]=e0; sbuf[pb+1]=e1; sbuf[pb+2]=e2; sbuf[pb+3]=e3;
            sbuf[pb+4]=e4; sbuf[pb+5]=e5; sbuf[pb+6]=e6; sbuf[pb+7]=e7;
        }
        __syncthreads();
    }

    for (int s = tid; s < KSEL; s += 1024) {
        u64 ck = sbuf[sphys(s)];
        int a = (int)(u32)ck;
        float score = probs[((size_t)b * A + a) * 2 + 1];
        float4 an = ((const float4*)anchors)[a];
        float4 dl = ((const float4*)deltas)[(size_t)b * A + a];
        float h = an.z - an.x, w = an.w - an.y;
        float cy = an.x + 0.5f * h + dl.x * 0.1f * h;
        float cx = an.y + 0.5f * w + dl.y * 0.1f * w;
        h *= expf(dl.z * 0.2f);
        w *= expf(dl.w * 0.2f);
        float y1 = cy - 0.5f * h, x1 = cx - 0.5f * w;
        float y2 = y1 + h,        x2 = x1 + w;
        y1 = fminf(fmaxf(y1, 0.f), 1024.f);
        x1 = fminf(fmaxf(x1, 0.f), 1024.f);
        y2 = fminf(fmaxf(y2, 0.f), 1024.f);
        x2 = fminf(fmaxf(x2, 0.f), 1024.f);
        ((float4*)boxes_sel)[(size_t)b * KSEL + s] = make_float4(y1, x1, y2, x2);
        scores_sel[(size_t)b * KSEL + s] = score;
    }
}

// ---------------- K4: suppression mask matrix (upper triangle only) ----------------
__global__ __launch_bounds__(64)
void k_iou(const float* __restrict__ boxes_sel, u64* __restrict__ mask)
{
    __shared__ float4 rowb[64];
    int t = threadIdx.x;
    int bi = blockIdx.x, bj = blockIdx.y, b = blockIdx.z;
    if (bj < bi) return;
    const float4* boxes = (const float4*)boxes_sel + (size_t)b * KSEL;
    int ri = bi * 64 + t;
    int j  = bj * 64 + t;
    rowb[t] = (ri < KSEL) ? boxes[ri] : make_float4(0.f, 0.f, 0.f, 0.f);
    float4 cb = (j < KSEL) ? boxes[j] : make_float4(0.f, 0.f, 0.f, 0.f);
    float areaC = (cb.z - cb.x) * (cb.w - cb.y);
    __syncthreads();
    u64 myword = 0;
    for (int r = 0; r < 64; ++r) {
        float4 rb = rowb[r];
        float areaR = (rb.z - rb.x) * (rb.w - rb.y);
        float iy1 = fmaxf(rb.x, cb.x), ix1 = fmaxf(rb.y, cb.y);
        float iy2 = fminf(rb.z, cb.z), ix2 = fminf(rb.w, cb.w);
        float inter = fmaxf(iy2 - iy1, 0.f) * fmaxf(ix2 - ix1, 0.f);
        float uni = fmaxf(areaR + areaC - inter, 1e-10f);
        bool sup = (j < KSEL) && (inter > 0.7f * uni);
        u64 word = __ballot(sup ? 1 : 0);
        if (r == t) myword = word;
    }
    if (ri < KSEL) mask[((size_t)b * KSEL + ri) * NW + bj] = myword;
}

// ---------------- K5: greedy NMS (asm-clustered dwordx4 row loads) + fused output ----------------
__global__ __launch_bounds__(64, 1)
void k_nms_out(const u64* __restrict__ mask,
               const float* __restrict__ boxes_sel, const float* __restrict__ scores_sel,
               float* __restrict__ out, int B)
{
    __shared__ int ki[PC];
    const int lane = threadIdx.x;
    const int b = blockIdx.x;
    const u64* mb = mask + (size_t)b * KSEL * NW;
    const u64 wmA = (2 * lane     < NW) ? ~0ULL : 0ULL;
    const u64 wmB = (2 * lane + 1 < NW) ? ~0ULL : 0ULL;

    u64 remvA = 0, remvB = 0;          // lane l: removal words 2l, 2l+1
    int kept = 0;
    u64 mcur = mb[(size_t)lane * NW];  // chunk 0 diagonal word

    for (int c = 0; c < NW; ++c) {
        int rin = (c + 1) * 64 + lane;                       // prefetch next diagonal
        u64 mnext = (c + 1 < NW && rin < KSEL) ? mb[(size_t)rin * NW + (c + 1)] : 0ULL;

        u64 r = (c & 1) ? bcast64(remvB, c >> 1) : bcast64(remvA, c >> 1);
        int rbn = KSEL - c * 64;
        u64 valid = (rbn >= 64) ? ~0ULL : ((1ULL << rbn) - 1ULL);
        u64 pend = valid & ~r;
        u64 keep = 0;
        while (pend) {                                       // wave-uniform greedy resolve
            int bb = (int)(__ffsll((unsigned long long)pend) - 1);
            keep |= 1ULL << bb;
            u64 sup = bcast64(mcur, bb);
            pend &= ~(sup | (1ULL << bb));
        }
        int m = __popcll((unsigned long long)keep);
        int mybit = selbit64(keep, lane);                    // lane q -> q-th kept bit
        if (lane < m && kept + lane < PC) ki[kept + lane] = c * 64 + mybit;
        kept += m;
        if (kept >= PC) { kept = PC; break; }
        if (c + 1 == NW) break;

        if (m) {
            const int cbase = c * 64;
            const int mm = m - 1;
            int nb8 = (m + 7) >> 3;
            for (int j = 0; j < nb8; ++j) {
                int qb = j * 8;
                int i0 = qb     > mm ? mm : qb;
                int i1 = qb + 1 > mm ? mm : qb + 1;
                int i2 = qb + 2 > mm ? mm : qb + 2;
                int i3 = qb + 3 > mm ? mm : qb + 3;
                int i4 = qb + 4 > mm ? mm : qb + 4;
                int i5 = qb + 5 > mm ? mm : qb + 5;
                int i6 = qb + 6 > mm ? mm : qb + 6;
                int i7 = qb + 7 > mm ? mm : qb + 7;
                int r0 = __builtin_amdgcn_readlane(mybit, i0);
                int r1 = __builtin_amdgcn_readlane(mybit, i1);
                int r2 = __builtin_amdgcn_readlane(mybit, i2);
                int r3 = __builtin_amdgcn_readlane(mybit, i3);
                int r4 = __builtin_amdgcn_readlane(mybit, i4);
                int r5 = __builtin_amdgcn_readlane(mybit, i5);
                int r6 = __builtin_amdgcn_readlane(mybit, i6);
                int r7 = __builtin_amdgcn_readlane(mybit, i7);
                const u64* p0 = mb + (size_t)(cbase + r0) * NW + 2 * lane;
                const u64* p1 = mb + (size_t)(cbase + r1) * NW + 2 * lane;
                const u64* p2 = mb + (size_t)(cbase + r2) * NW + 2 * lane;
                const u64* p3 = mb + (size_t)(cbase + r3) * NW + 2 * lane;
                const u64* p4 = mb + (size_t)(cbase + r4) * NW + 2 * lane;
                const u64* p5 = mb + (size_t)(cbase + r5) * NW + 2 * lane;
                const u64* p6 = mb + (size_t)(cbase + r6) * NW + 2 * lane;
                const u64* p7 = mb + (size_t)(cbase + r7) * NW + 2 * lane;
                int4 d0, d1, d2, d3, d4, d5, d6, d7;
                asm volatile(
                    "global_load_dwordx4 %0, %8, off\n\t"
                    "global_load_dwordx4 %1, %9, off\n\t"
                    "global_load_dwordx4 %2, %10, off\n\t"
                    "global_load_dwordx4 %3, %11, off\n\t"
                    "global_load_dwordx4 %4, %12, off\n\t"
                    "global_load_dwordx4 %5, %13, off\n\t"
                    "global_load_dwordx4 %6, %14, off\n\t"
                    "global_load_dwordx4 %7, %15, off\n\t"
                    "s_waitcnt vmcnt(0)"
                    : "=&v"(d0), "=&v"(d1), "=&v"(d2), "=&v"(d3),
                      "=&v"(d4), "=&v"(d5), "=&v"(d6), "=&v"(d7)
                    : "v"(p0), "v"(p1), "v"(p2), "v"(p3),
                      "v"(p4), "v"(p5), "v"(p6), "v"(p7)
                    : "memory");
                u64 aacc = 0, bacc = 0;
                u64 lo, hi, live;
                live = (qb + 0 < m) ? ~0ULL : 0ULL;
                lo = ((u64)(u32)d0.y << 32) | (u32)d0.x;
                hi = ((u64)(u32)d0.w << 32) | (u32)d0.z;
                aacc |= lo & live; bacc |= hi & live;
                live = (qb + 1 < m) ? ~0ULL : 0ULL;
                lo = ((u64)(u32)d1.y << 32) | (u32)d1.x;
                hi = ((u64)(u32)d1.w << 32) | (u32)d1.z;
                aacc |= lo & live; bacc |= hi & live;
                live = (qb + 2 < m) ? ~0ULL : 0ULL;
                lo = ((u64)(u32)d2.y << 32) | (u32)d2.x;
                hi = ((u64)(u32)d2.w << 32) | (u32)d2.z;
                aacc |= lo & live; bacc |= hi & live;
                live = (qb + 3 < m) ? ~0ULL : 0ULL;
                lo = ((u64)(u32)d3.y << 32) | (u32)d3.x;
                hi = ((u64)(u32)d3.w << 32) | (u32)d3.z;
                aacc |= lo & live; bacc |= hi & live;
                live = (qb + 4 < m) ? ~0ULL : 0ULL;
                lo = ((u64)(u32)d4.y << 32) | (u32)d4.x;
                hi = ((u64)(u32)d4.w << 32) | (u32)d4.z;
                aacc |= lo & live; bacc |= hi & live;
                live = (qb + 5 < m) ? ~0ULL : 0ULL;
                lo = ((u64)(u32)d5.y << 32) | (u32)d5.x;
                hi = ((u64)(u32)d5.w << 32) | (u32)d5.z;
                aacc |= lo & live; bacc |= hi & live;
                live = (qb + 6 < m) ? ~0ULL : 0ULL;
                lo = ((u64)(u32)d6.y << 32) | (u32)d6.x;
                hi = ((u64)(u32)d6.w << 32) | (u32)d6.z;
                aacc |= lo & live; bacc |= hi & live;
                live = (qb + 7 < m) ? ~0ULL : 0ULL;
                lo = ((u64)(u32)d7.y << 32) | (u32)d7.x;
                hi = ((u64)(u32)d7.w << 32) | (u32)d7.z;
                aacc |= lo & live; bacc |= hi & live;
                remvA |= aacc & wmA;
                remvB |= bacc & wmB;
            }
        }
        mcur = mnext;
    }

    // ---- fused output: gather kept, normalize, zero tail, write n ----
    const float4* bx = (const float4*)boxes_sel + (size_t)b * KSEL;
    const float*  sc = scores_sel + (size_t)b * KSEL;
    float4* ob = (float4*)(out + (size_t)b * PC * 4);
    float*  os = out + (size_t)B * PC * 4 + (size_t)b * PC;
    for (int s = lane; s < PC; s += 64) {
        float4 v = make_float4(0.f, 0.f, 0.f, 0.f);
        float sv = 0.f;
        if (s < kept) {
            int i = ki[s];
            float4 t = bx[i];
            v = make_float4(t.x * (1.f/1024.f), t.y * (1.f/1024.f),
                            t.z * (1.f/1024.f), t.w * (1.f/1024.f));
            sv = sc[i];
        }
        ob[s] = v;
        os[s] = sv;
    }
    if (lane == 0) out[(size_t)B * PC * 5 + b] = (float)kept;
}

extern "C" void kernel_launch(void* const* d_in, const int* in_sizes, int n_in,
                              void* d_out, int out_size, void* d_ws, size_t ws_size,
                              hipStream_t stream)
{
    const float* probs   = (const float*)d_in[0];
    const float* deltas  = (const float*)d_in[1];
    const float* anchors = (const float*)d_in[2];
    int A = in_sizes[2] / 4;
    int B = in_sizes[0] / (2 * A);

    char* w = (char*)d_ws;
    size_t off = 0;
    // zero region (single tiny memset): hist8a | hist8b | cnt
    u32* hist8a = (u32*)(w + off);     off += (size_t)B * 256 * sizeof(u32);
    u32* hist8b = (u32*)(w + off);     off += (size_t)B * 256 * sizeof(u32);
    u32* cnt    = (u32*)(w + off);     off += (size_t)B * sizeof(u32);
    size_t zero_bytes = off;
    off = (off + 15) & ~(size_t)15;
    u32* keys = (u32*)(w + off);       off += (size_t)B * A * sizeof(u32);
    off = (off + 15) & ~(size_t)15;
    u64* cand = (u64*)(w + off);       off += (size_t)B * CAP * sizeof(u64);
    float* boxes_sel  = (float*)(w + off); off += (size_t)B * KSEL * 4 * sizeof(float);
    float* scores_sel = (float*)(w + off); off += (size_t)B * KSEL * sizeof(float);
    off = (off + 15) & ~(size_t)15;
    u64* mask = (u64*)(w + off);           off += (size_t)B * KSEL * NW * sizeof(u64);
    off += 1024;                           // guard: dwordx4 row loads overread past word 93

    hipMemsetAsync(hist8a, 0, zero_bytes, stream);

    dim3 gCH((A + CH - 1) / CH, B);
    dim3 gA((A + 255) / 256, B);
    k_keys_hist8<<<gCH, 256, 0, stream>>>(probs, keys, hist8a, A);
    k_hist8b<<<gCH, 256, 0, stream>>>(keys, hist8a, hist8b, A);
    k_collect<<<gA, 256, 0, stream>>>(keys, hist8a, hist8b, cnt, cand, A);
    k_sortdecode<<<B, 1024, 0, stream>>>(probs, deltas, anchors, cand, cnt,
                                         boxes_sel, scores_sel, A);
    k_iou<<<dim3(NW, NW, B), 64, 0, stream>>>(boxes_sel, mask);
    k_nms_out<<<B, 64, 0, stream>>>(mask, boxes_sel, scores_sel, (float*)d_out, B);
}